// Round 2
// baseline (259.618 us; speedup 1.0000x reference)
//
#include <hip/hip_runtime.h>
#include <hip/hip_bf16.h>

#define N_TOK 4096
#define NH 8
#define HD 32
#define CDIM 256
#define QKV_N 768
#define KSPLIT 2
#define SCALE_F 0.17677669529663687f  // 32^-0.5

typedef float  f32x4  __attribute__((ext_vector_type(4)));
typedef int    i32x4  __attribute__((ext_vector_type(4)));
typedef short  s16x4  __attribute__((ext_vector_type(4)));
typedef __bf16 bf16x8 __attribute__((ext_vector_type(8)));

union FragI { i32x4 i; bf16x8 b; };
union FragH { struct { s16x4 lo, hi; } s; bf16x8 b; };

// ---------------------------------------------------------------------------
// keep mask: keep = 3x3 neighborhood OR of (dbz >= 15), per frame (zero pad).
// bias = 0 (keep) / -30000 (masked key -> exp underflows to exact 0).
__global__ __launch_bounds__(256) void prep_mask(const float* __restrict__ dbz,
                                                 float* __restrict__ bias,
                                                 int* __restrict__ keepi) {
  int n = blockIdx.x * 256 + threadIdx.x;
  if (n >= N_TOK) return;
  int t = n >> 10, rc = n & 1023, r = rc >> 5, c = rc & 31;
  bool keep = false;
  #pragma unroll
  for (int dr = -1; dr <= 1; dr++) {
    #pragma unroll
    for (int dc = -1; dc <= 1; dc++) {
      int rr = r + dr, cc = c + dc;
      if (rr >= 0 && rr < 32 && cc >= 0 && cc < 32)
        keep = keep || (dbz[t * 1024 + rr * 32 + cc] >= 15.0f);
    }
  }
  bias[n]  = keep ? 0.0f : -30000.0f;
  keepi[n] = keep ? 1 : 0;
}

// ---------------------------------------------------------------------------
// fp32 -> bf16 convert; first n_scaled elements multiplied by scale.
__global__ __launch_bounds__(256) void cvt_bf16(const float* __restrict__ src,
                                                __bf16* __restrict__ dst,
                                                int n, int n_scaled, float scale) {
  int i = blockIdx.x * 256 + threadIdx.x;
  if (i >= n) return;
  float v = src[i];
  if (i < n_scaled) v *= scale;
  dst[i] = (__bf16)v;
}

// ---------------------------------------------------------------------------
// QKV GEMM: (4096 x 256) @ (768 x 256)^T via mfma 16x16x32 bf16.
__global__ __launch_bounds__(256) void qkv_gemm(const __bf16* __restrict__ xb,
                                                const __bf16* __restrict__ wb,
                                                __bf16* __restrict__ qb,
                                                __bf16* __restrict__ kb,
                                                __bf16* __restrict__ vt) {
  int wave = threadIdx.x >> 6, lane = threadIdx.x & 63;
  int quad = lane >> 4, l16 = lane & 15;
  int m0 = blockIdx.x * 64 + wave * 16;
  int n0 = blockIdx.y * 64;

  f32x4 acc[4] = {};
  for (int kk = 0; kk < CDIM; kk += 32) {
    FragI af;
    af.i = *(const i32x4*)(xb + (size_t)(m0 + l16) * CDIM + kk + quad * 8);
    #pragma unroll
    for (int nt = 0; nt < 4; nt++) {
      FragI bfr;
      bfr.i = *(const i32x4*)(wb + (size_t)(n0 + nt * 16 + l16) * CDIM + kk + quad * 8);
      acc[nt] = __builtin_amdgcn_mfma_f32_16x16x32_bf16(af.b, bfr.b, acc[nt], 0, 0, 0);
    }
  }
  #pragma unroll
  for (int nt = 0; nt < 4; nt++) {
    int c = n0 + nt * 16 + l16;            // output channel in [0,768)
    int which = c >> 8, rem = c & 255, head = rem >> 5, d = rem & 31;
    #pragma unroll
    for (int r = 0; r < 4; r++) {
      int m = m0 + quad * 4 + r;           // token
      __bf16 v = (__bf16)acc[nt][r];
      if (which == 0)      qb[((size_t)head * N_TOK + m) * HD + d] = v;
      else if (which == 1) kb[((size_t)head * N_TOK + m) * HD + d] = v;
      else                 vt[((size_t)head * HD + d) * N_TOK + m] = v;
    }
  }
}

// ---------------------------------------------------------------------------
// Attention, no-max softmax (scores are O(1); exp(s+bias) cannot overflow;
// masked keys: exp(s-30000) == 0 exactly). Split-K x2; partials are directly
// summable since there is no per-chunk max.
// One wave = 16 queries x 2048 keys. S^T = K*Q^T (C-layout col = query).
// PV computed SWAPPED: O^T = mfma(V^T_frag, P_frag) so col = query = l16 ->
// l-normalization and output need no cross-lane ops. Per-lane l partial,
// reduced with 2 shfl_xor at the end only.
__global__ __launch_bounds__(256) void attn_kernel(const __bf16* __restrict__ qb,
                                                   const __bf16* __restrict__ kb,
                                                   const __bf16* __restrict__ vt,
                                                   const float* __restrict__ bias,
                                                   float* __restrict__ o_part,
                                                   float* __restrict__ l_part) {
  int head = blockIdx.y, ks = blockIdx.z;
  int wave = threadIdx.x >> 6, lane = threadIdx.x & 63;
  int quad = lane >> 4, l16 = lane & 15;
  int q0 = blockIdx.x * 64 + wave * 16;
  const int kbeg = ks * (N_TOK / KSPLIT), kend = kbeg + N_TOK / KSPLIT;

  const __bf16* qh = qb + (size_t)head * N_TOK * HD;
  const __bf16* kh = kb + (size_t)head * N_TOK * HD;
  const __bf16* vh = vt + (size_t)head * HD * N_TOK;

  FragI qf;
  qf.i = *(const i32x4*)(qh + (size_t)(q0 + l16) * HD + quad * 8);

  float lsum = 0.0f;
  f32x4 o_lo = {0.f, 0.f, 0.f, 0.f}, o_hi = {0.f, 0.f, 0.f, 0.f};

  // current-iteration fragments (prefetched)
  FragI ka_c, kb_c;
  FragH vlo_c, vhi_c;
  f32x4 ba_c, bb_c;
  {
    int k0 = kbeg;
    ka_c.i = *(const i32x4*)(kh + (size_t)(k0 + l16) * HD + quad * 8);
    kb_c.i = *(const i32x4*)(kh + (size_t)(k0 + 16 + l16) * HD + quad * 8);
    const __bf16* vp = vh + (size_t)l16 * N_TOK + k0 + quad * 4;
    vlo_c.s.lo = *(const s16x4*)(vp);
    vlo_c.s.hi = *(const s16x4*)(vp + 16);
    const __bf16* vp2 = vh + (size_t)(16 + l16) * N_TOK + k0 + quad * 4;
    vhi_c.s.lo = *(const s16x4*)(vp2);
    vhi_c.s.hi = *(const s16x4*)(vp2 + 16);
    ba_c = *(const f32x4*)(bias + k0 + quad * 4);
    bb_c = *(const f32x4*)(bias + k0 + 16 + quad * 4);
  }

  for (int k0 = kbeg; k0 < kend; k0 += 32) {
    // prefetch next iteration (wraps to kbeg on last iter; result unused)
    int kp = (k0 + 32 < kend) ? k0 + 32 : kbeg;
    FragI ka_n, kb_n;
    FragH vlo_n, vhi_n;
    f32x4 ba_n, bb_n;
    ka_n.i = *(const i32x4*)(kh + (size_t)(kp + l16) * HD + quad * 8);
    kb_n.i = *(const i32x4*)(kh + (size_t)(kp + 16 + l16) * HD + quad * 8);
    const __bf16* vp = vh + (size_t)l16 * N_TOK + kp + quad * 4;
    vlo_n.s.lo = *(const s16x4*)(vp);
    vlo_n.s.hi = *(const s16x4*)(vp + 16);
    const __bf16* vp2 = vh + (size_t)(16 + l16) * N_TOK + kp + quad * 4;
    vhi_n.s.lo = *(const s16x4*)(vp2);
    vhi_n.s.hi = *(const s16x4*)(vp2 + 16);
    ba_n = *(const f32x4*)(bias + kp + quad * 4);
    bb_n = *(const f32x4*)(bias + kp + 16 + quad * 4);

    f32x4 z = {0.f, 0.f, 0.f, 0.f};
    // S^T tiles: lane holds q = l16, keys quad*4+r (sa) / 16+quad*4+r (sb)
    f32x4 sa = __builtin_amdgcn_mfma_f32_16x16x32_bf16(ka_c.b, qf.b, z, 0, 0, 0);
    f32x4 sb = __builtin_amdgcn_mfma_f32_16x16x32_bf16(kb_c.b, qf.b, z, 0, 0, 0);

    float p[8];
    #pragma unroll
    for (int r = 0; r < 4; r++) {
      p[r]     = __expf(sa[r] + ba_c[r]);
      p[4 + r] = __expf(sb[r] + bb_c[r]);
    }
    #pragma unroll
    for (int j = 0; j < 8; j++) lsum += p[j];

    FragI pf;
    #pragma unroll
    for (int j = 0; j < 8; j++) pf.b[j] = (__bf16)p[j];

    // swapped operands: A = V^T frag (row=d), B = P (col=query=l16)
    o_lo = __builtin_amdgcn_mfma_f32_16x16x32_bf16(vlo_c.b, pf.b, o_lo, 0, 0, 0);
    o_hi = __builtin_amdgcn_mfma_f32_16x16x32_bf16(vhi_c.b, pf.b, o_hi, 0, 0, 0);

    ka_c = ka_n; kb_c = kb_n;
    vlo_c = vlo_n; vhi_c = vhi_n;
    ba_c = ba_n; bb_c = bb_n;
  }

  // full l(q) for q = l16: sum the 4 quads
  lsum += __shfl_xor(lsum, 16);
  lsum += __shfl_xor(lsum, 32);

  // O^T regs: o_lo[r] = O[q=l16][d=quad*4+r], o_hi -> d+16. Store fp32 partial.
  float* op = o_part + ((size_t)(ks * NH + head) * N_TOK + q0 + l16) * HD;
  *(f32x4*)(op + quad * 4)      = o_lo;
  *(f32x4*)(op + 16 + quad * 4) = o_hi;
  if (quad == 0)
    l_part[(size_t)(ks * NH + head) * N_TOK + q0 + l16] = lsum;
}

// ---------------------------------------------------------------------------
// Combine split-K partials: ob[q, h*32+d] = (o0+o1) / (l0+l1)   (bf16)
__global__ __launch_bounds__(256) void attn_combine(const float* __restrict__ o_part,
                                                    const float* __restrict__ l_part,
                                                    __bf16* __restrict__ ob) {
  int idx = blockIdx.x * 256 + threadIdx.x;  // over NH*N_TOK*HD = 1M
  int d = idx & 31, q = (idx >> 5) & (N_TOK - 1), h = idx >> 17;
  float o0 = o_part[((size_t)h * N_TOK + q) * HD + d];
  float o1 = o_part[((size_t)(NH + h) * N_TOK + q) * HD + d];
  float l0 = l_part[(size_t)h * N_TOK + q];
  float l1 = l_part[(size_t)(NH + h) * N_TOK + q];
  ob[(size_t)q * CDIM + h * HD + d] = (__bf16)((o0 + o1) / (l0 + l1));
}

// ---------------------------------------------------------------------------
// Output projection: out = (keep ? attn@Wp^T + b : 0) + x   (fp32 out)
__global__ __launch_bounds__(256) void proj_gemm(const __bf16* __restrict__ ob,
                                                 const __bf16* __restrict__ wb,
                                                 const float* __restrict__ pb,
                                                 const int* __restrict__ keepi,
                                                 const float* __restrict__ x,
                                                 float* __restrict__ out) {
  int wave = threadIdx.x >> 6, lane = threadIdx.x & 63;
  int quad = lane >> 4, l16 = lane & 15;
  int m0 = blockIdx.x * 64 + wave * 16;
  int n0 = blockIdx.y * 64;

  f32x4 acc[4] = {};
  for (int kk = 0; kk < CDIM; kk += 32) {
    FragI af;
    af.i = *(const i32x4*)(ob + (size_t)(m0 + l16) * CDIM + kk + quad * 8);
    #pragma unroll
    for (int nt = 0; nt < 4; nt++) {
      FragI bfr;
      bfr.i = *(const i32x4*)(wb + (size_t)(n0 + nt * 16 + l16) * CDIM + kk + quad * 8);
      acc[nt] = __builtin_amdgcn_mfma_f32_16x16x32_bf16(af.b, bfr.b, acc[nt], 0, 0, 0);
    }
  }
  #pragma unroll
  for (int nt = 0; nt < 4; nt++) {
    int c = n0 + nt * 16 + l16;
    #pragma unroll
    for (int r = 0; r < 4; r++) {
      int m = m0 + quad * 4 + r;
      float v = acc[nt][r] + pb[c];
      v = keepi[m] ? v : 0.0f;
      out[(size_t)m * CDIM + c] = v + x[(size_t)m * CDIM + c];
    }
  }
}

// ---------------------------------------------------------------------------
extern "C" void kernel_launch(void* const* d_in, const int* in_sizes, int n_in,
                              void* d_out, int out_size, void* d_ws, size_t ws_size,
                              hipStream_t stream) {
  const float* x      = (const float*)d_in[0];
  const float* dbz    = (const float*)d_in[1];
  const float* qkv_w  = (const float*)d_in[2];
  const float* proj_w = (const float*)d_in[3];
  const float* proj_b = (const float*)d_in[4];
  float* out = (float*)d_out;

  char* w = (char*)d_ws;
  __bf16* xb     = (__bf16*)(w);                       // 2 MB
  __bf16* qb     = (__bf16*)(w + (2u << 20));          // 2 MB
  __bf16* kb     = (__bf16*)(w + (4u << 20));          // 2 MB
  __bf16* vt     = (__bf16*)(w + (6u << 20));          // 2 MB
  __bf16* ob     = (__bf16*)(w + (8u << 20));          // 2 MB
  __bf16* wqkvb  = (__bf16*)(w + (10u << 20));         // 384 KB
  __bf16* wprojb = (__bf16*)(w + (10u << 20) + 393216);  // 128 KB
  float*  bias   = (float*)(w + (10u << 20) + 393216 + 131072);  // 16 KB
  int*    keepi  = (int*)(w + (10u << 20) + 393216 + 131072 + 16384);  // 16 KB
  float*  o_part = (float*)(w + (12u << 20));          // 8 MB (2x8x4096x32 f32)
  float*  l_part = (float*)(w + (20u << 20));          // 256 KB

  prep_mask<<<dim3(16), dim3(256), 0, stream>>>(dbz, bias, keepi);
  cvt_bf16<<<dim3((N_TOK * CDIM + 255) / 256), dim3(256), 0, stream>>>(
      x, xb, N_TOK * CDIM, 0, 1.0f);
  cvt_bf16<<<dim3((QKV_N * CDIM + 255) / 256), dim3(256), 0, stream>>>(
      qkv_w, wqkvb, QKV_N * CDIM, CDIM * CDIM, SCALE_F);  // scale Q rows
  cvt_bf16<<<dim3((CDIM * CDIM + 255) / 256), dim3(256), 0, stream>>>(
      proj_w, wprojb, CDIM * CDIM, 0, 1.0f);

  qkv_gemm<<<dim3(N_TOK / 64, QKV_N / 64), dim3(256), 0, stream>>>(
      xb, wqkvb, qb, kb, vt);
  attn_kernel<<<dim3(N_TOK / 64, NH, KSPLIT), dim3(256), 0, stream>>>(
      qb, kb, vt, bias, o_part, l_part);
  attn_combine<<<dim3(NH * N_TOK * HD / 256), dim3(256), 0, stream>>>(
      o_part, l_part, ob);
  proj_gemm<<<dim3(N_TOK / 64, CDIM / 64), dim3(256), 0, stream>>>(
      ob, wprojb, proj_b, keepi, x, out);
}

// Round 3
// 153.604 us; speedup vs baseline: 1.6902x; 1.6902x over previous
//
#include <hip/hip_runtime.h>
#include <hip/hip_bf16.h>

#define N_TOK 4096
#define NH 8
#define HD 32
#define CDIM 256
#define QKV_N 768
#define KSPLIT 2
#define VT_STRIDE 4128              // padded: breaks 8192B power-of-2 channel/set stride
#define SCALE_F 0.17677669529663687f  // 32^-0.5

typedef float  f32x4  __attribute__((ext_vector_type(4)));
typedef int    i32x4  __attribute__((ext_vector_type(4)));
typedef short  s16x4  __attribute__((ext_vector_type(4)));
typedef __bf16 bf16x8 __attribute__((ext_vector_type(8)));

union FragI { i32x4 i; bf16x8 b; };
union FragH { struct { s16x4 lo, hi; } s; bf16x8 b; };

// ---------------------------------------------------------------------------
// keep mask: keep = 3x3 neighborhood OR of (dbz >= 15), per frame (zero pad).
__global__ __launch_bounds__(256) void prep_mask(const float* __restrict__ dbz,
                                                 float* __restrict__ bias,
                                                 int* __restrict__ keepi) {
  int n = blockIdx.x * 256 + threadIdx.x;
  if (n >= N_TOK) return;
  int t = n >> 10, rc = n & 1023, r = rc >> 5, c = rc & 31;
  bool keep = false;
  #pragma unroll
  for (int dr = -1; dr <= 1; dr++) {
    #pragma unroll
    for (int dc = -1; dc <= 1; dc++) {
      int rr = r + dr, cc = c + dc;
      if (rr >= 0 && rr < 32 && cc >= 0 && cc < 32)
        keep = keep || (dbz[t * 1024 + rr * 32 + cc] >= 15.0f);
    }
  }
  bias[n]  = keep ? 0.0f : -30000.0f;
  keepi[n] = keep ? 1 : 0;
}

// ---------------------------------------------------------------------------
__global__ __launch_bounds__(256) void cvt_bf16(const float* __restrict__ src,
                                                __bf16* __restrict__ dst,
                                                int n, int n_scaled, float scale) {
  int i = blockIdx.x * 256 + threadIdx.x;
  if (i >= n) return;
  float v = src[i];
  if (i < n_scaled) v *= scale;
  dst[i] = (__bf16)v;
}

// ---------------------------------------------------------------------------
// QKV GEMM: (4096 x 256) @ (768 x 256)^T via mfma 16x16x32 bf16.
// q,k -> [h][n][d]; v -> [h][d][VT_STRIDE] transposed+padded.
__global__ __launch_bounds__(256) void qkv_gemm(const __bf16* __restrict__ xb,
                                                const __bf16* __restrict__ wb,
                                                __bf16* __restrict__ qb,
                                                __bf16* __restrict__ kb,
                                                __bf16* __restrict__ vt) {
  int wave = threadIdx.x >> 6, lane = threadIdx.x & 63;
  int quad = lane >> 4, l16 = lane & 15;
  int m0 = blockIdx.x * 64 + wave * 16;
  int n0 = blockIdx.y * 64;

  f32x4 acc[4] = {};
  for (int kk = 0; kk < CDIM; kk += 32) {
    FragI af;
    af.i = *(const i32x4*)(xb + (size_t)(m0 + l16) * CDIM + kk + quad * 8);
    #pragma unroll
    for (int nt = 0; nt < 4; nt++) {
      FragI bfr;
      bfr.i = *(const i32x4*)(wb + (size_t)(n0 + nt * 16 + l16) * CDIM + kk + quad * 8);
      acc[nt] = __builtin_amdgcn_mfma_f32_16x16x32_bf16(af.b, bfr.b, acc[nt], 0, 0, 0);
    }
  }
  #pragma unroll
  for (int nt = 0; nt < 4; nt++) {
    int c = n0 + nt * 16 + l16;            // output channel in [0,768)
    int which = c >> 8, rem = c & 255, head = rem >> 5, d = rem & 31;
    #pragma unroll
    for (int r = 0; r < 4; r++) {
      int m = m0 + quad * 4 + r;           // token
      __bf16 v = (__bf16)acc[nt][r];
      if (which == 0)      qb[((size_t)head * N_TOK + m) * HD + d] = v;
      else if (which == 1) kb[((size_t)head * N_TOK + m) * HD + d] = v;
      else                 vt[((size_t)head * HD + d) * VT_STRIDE + m] = v;
    }
  }
}

// ---------------------------------------------------------------------------
// Attention v3: no-max softmax (scores O(1), masked keys exp(s-30000)==0).
// Block = 64 queries x one head x one K-split half. The pathological V^T
// global loads (8192B stride -> same L1 set / L2 channel, 4x redundant per
// block) are replaced by block-cooperative LDS staging: 128-key V^T tile,
// double-buffered, padded LDS rows (136 elems) to spread banks.
// K stays global (64B-contiguous rows) with rolling register prefetch.
__global__ __launch_bounds__(256) void attn_kernel(const __bf16* __restrict__ qb,
                                                   const __bf16* __restrict__ kb,
                                                   const __bf16* __restrict__ vt,
                                                   const float* __restrict__ bias,
                                                   float* __restrict__ o_part,
                                                   float* __restrict__ l_part) {
  __shared__ __bf16 vtile[2][32][136];     // 2 x 8.5KB, padded stride 272B

  int head = blockIdx.y, ks = blockIdx.z;
  int wave = threadIdx.x >> 6, lane = threadIdx.x & 63;
  int quad = lane >> 4, l16 = lane & 15;
  int q0 = blockIdx.x * 64 + wave * 16;
  const int kbeg = ks * (N_TOK / KSPLIT), kend = kbeg + N_TOK / KSPLIT;
  const int NTILES = (N_TOK / KSPLIT) / 128;   // 16 tiles of 128 keys

  const __bf16* qh = qb + (size_t)head * N_TOK * HD;
  const __bf16* kh = kb + (size_t)head * N_TOK * HD;
  const __bf16* vh = vt + (size_t)head * HD * VT_STRIDE;

  FragI qf;
  qf.i = *(const i32x4*)(qh + (size_t)(q0 + l16) * HD + quad * 8);

  // stage V^T tile 0: thread t covers 16B chunks t and t+256 of the 8KB tile
  {
    int c1 = threadIdx.x, c2 = threadIdx.x + 256;
    i32x4 s1 = *(const i32x4*)(vh + (size_t)(c1 >> 4) * VT_STRIDE + kbeg + (c1 & 15) * 8);
    i32x4 s2 = *(const i32x4*)(vh + (size_t)(c2 >> 4) * VT_STRIDE + kbeg + (c2 & 15) * 8);
    *(i32x4*)&vtile[0][c1 >> 4][(c1 & 15) * 8] = s1;
    *(i32x4*)&vtile[0][c2 >> 4][(c2 & 15) * 8] = s2;
  }
  __syncthreads();

  float lsum = 0.0f;
  f32x4 o_lo = {0.f, 0.f, 0.f, 0.f}, o_hi = {0.f, 0.f, 0.f, 0.f};

  // rolling K/bias prefetch
  FragI ka_c, kb_c;
  f32x4 ba_c, bb_c;
  ka_c.i = *(const i32x4*)(kh + (size_t)(kbeg + l16) * HD + quad * 8);
  kb_c.i = *(const i32x4*)(kh + (size_t)(kbeg + 16 + l16) * HD + quad * 8);
  ba_c = *(const f32x4*)(bias + kbeg + quad * 4);
  bb_c = *(const f32x4*)(bias + kbeg + 16 + quad * 4);

  for (int tile = 0; tile < NTILES; tile++) {
    int buf = tile & 1;
    bool haveNext = (tile + 1 < NTILES);

    // issue next V^T tile global loads (latency overlapped with compute)
    i32x4 s1, s2;
    if (haveNext) {
      int t0n = kbeg + (tile + 1) * 128;
      int c1 = threadIdx.x, c2 = threadIdx.x + 256;
      s1 = *(const i32x4*)(vh + (size_t)(c1 >> 4) * VT_STRIDE + t0n + (c1 & 15) * 8);
      s2 = *(const i32x4*)(vh + (size_t)(c2 >> 4) * VT_STRIDE + t0n + (c2 & 15) * 8);
    }

    #pragma unroll
    for (int step = 0; step < 4; step++) {
      int k0 = kbeg + tile * 128 + step * 32;
      int kn = (k0 + 32 < kend) ? k0 + 32 : kbeg;   // wrap: last prefetch unused

      FragI ka_n, kb_n;
      f32x4 ba_n, bb_n;
      ka_n.i = *(const i32x4*)(kh + (size_t)(kn + l16) * HD + quad * 8);
      kb_n.i = *(const i32x4*)(kh + (size_t)(kn + 16 + l16) * HD + quad * 8);
      ba_n = *(const f32x4*)(bias + kn + quad * 4);
      bb_n = *(const f32x4*)(bias + kn + 16 + quad * 4);

      f32x4 z = {0.f, 0.f, 0.f, 0.f};
      // S^T tiles: lane holds q = l16, keys quad*4+r (sa) / 16+quad*4+r (sb)
      f32x4 sa = __builtin_amdgcn_mfma_f32_16x16x32_bf16(ka_c.b, qf.b, z, 0, 0, 0);
      f32x4 sb = __builtin_amdgcn_mfma_f32_16x16x32_bf16(kb_c.b, qf.b, z, 0, 0, 0);

      float p[8];
      #pragma unroll
      for (int r = 0; r < 4; r++) {
        p[r]     = __expf(sa[r] + ba_c[r]);
        p[4 + r] = __expf(sb[r] + bb_c[r]);
      }
      #pragma unroll
      for (int j = 0; j < 8; j++) lsum += p[j];

      FragI pf;
      #pragma unroll
      for (int j = 0; j < 8; j++) pf.b[j] = (__bf16)p[j];

      // V frags from LDS: rows d = l16 / 16+l16, keys step*32 + quad*4 (+16)
      FragH vlo, vhi;
      vlo.s.lo = *(const s16x4*)&vtile[buf][l16][step * 32 + quad * 4];
      vlo.s.hi = *(const s16x4*)&vtile[buf][l16][step * 32 + 16 + quad * 4];
      vhi.s.lo = *(const s16x4*)&vtile[buf][16 + l16][step * 32 + quad * 4];
      vhi.s.hi = *(const s16x4*)&vtile[buf][16 + l16][step * 32 + 16 + quad * 4];

      // swapped operands: A = V^T frag (row=d), B = P (col=query=l16)
      o_lo = __builtin_amdgcn_mfma_f32_16x16x32_bf16(vlo.b, pf.b, o_lo, 0, 0, 0);
      o_hi = __builtin_amdgcn_mfma_f32_16x16x32_bf16(vhi.b, pf.b, o_hi, 0, 0, 0);

      ka_c = ka_n; kb_c = kb_n; ba_c = ba_n; bb_c = bb_n;
    }

    if (haveNext) {
      int c1 = threadIdx.x, c2 = threadIdx.x + 256;
      *(i32x4*)&vtile[buf ^ 1][c1 >> 4][(c1 & 15) * 8] = s1;
      *(i32x4*)&vtile[buf ^ 1][c2 >> 4][(c2 & 15) * 8] = s2;
    }
    __syncthreads();
  }

  // full l(q) for q = l16: sum the 4 quads
  lsum += __shfl_xor(lsum, 16);
  lsum += __shfl_xor(lsum, 32);

  // O^T regs: o_lo[r] = O[q=l16][d=quad*4+r], o_hi -> d+16. fp32 partials.
  float* op = o_part + ((size_t)(ks * NH + head) * N_TOK + q0 + l16) * HD;
  *(f32x4*)(op + quad * 4)      = o_lo;
  *(f32x4*)(op + 16 + quad * 4) = o_hi;
  if (quad == 0)
    l_part[(size_t)(ks * NH + head) * N_TOK + q0 + l16] = lsum;
}

// ---------------------------------------------------------------------------
// Combine split-K partials: ob[q, h*32+d] = (o0+o1) / (l0+l1)   (bf16)
__global__ __launch_bounds__(256) void attn_combine(const float* __restrict__ o_part,
                                                    const float* __restrict__ l_part,
                                                    __bf16* __restrict__ ob) {
  int idx = blockIdx.x * 256 + threadIdx.x;  // over NH*N_TOK*HD = 1M
  int d = idx & 31, q = (idx >> 5) & (N_TOK - 1), h = idx >> 17;
  float o0 = o_part[((size_t)h * N_TOK + q) * HD + d];
  float o1 = o_part[((size_t)(NH + h) * N_TOK + q) * HD + d];
  float l0 = l_part[(size_t)h * N_TOK + q];
  float l1 = l_part[(size_t)(NH + h) * N_TOK + q];
  ob[(size_t)q * CDIM + h * HD + d] = (__bf16)((o0 + o1) / (l0 + l1));
}

// ---------------------------------------------------------------------------
// Output projection: out = (keep ? attn@Wp^T + b : 0) + x   (fp32 out)
__global__ __launch_bounds__(256) void proj_gemm(const __bf16* __restrict__ ob,
                                                 const __bf16* __restrict__ wb,
                                                 const float* __restrict__ pb,
                                                 const int* __restrict__ keepi,
                                                 const float* __restrict__ x,
                                                 float* __restrict__ out) {
  int wave = threadIdx.x >> 6, lane = threadIdx.x & 63;
  int quad = lane >> 4, l16 = lane & 15;
  int m0 = blockIdx.x * 64 + wave * 16;
  int n0 = blockIdx.y * 64;

  f32x4 acc[4] = {};
  for (int kk = 0; kk < CDIM; kk += 32) {
    FragI af;
    af.i = *(const i32x4*)(ob + (size_t)(m0 + l16) * CDIM + kk + quad * 8);
    #pragma unroll
    for (int nt = 0; nt < 4; nt++) {
      FragI bfr;
      bfr.i = *(const i32x4*)(wb + (size_t)(n0 + nt * 16 + l16) * CDIM + kk + quad * 8);
      acc[nt] = __builtin_amdgcn_mfma_f32_16x16x32_bf16(af.b, bfr.b, acc[nt], 0, 0, 0);
    }
  }
  #pragma unroll
  for (int nt = 0; nt < 4; nt++) {
    int c = n0 + nt * 16 + l16;
    #pragma unroll
    for (int r = 0; r < 4; r++) {
      int m = m0 + quad * 4 + r;
      float v = acc[nt][r] + pb[c];
      v = keepi[m] ? v : 0.0f;
      out[(size_t)m * CDIM + c] = v + x[(size_t)m * CDIM + c];
    }
  }
}

// ---------------------------------------------------------------------------
extern "C" void kernel_launch(void* const* d_in, const int* in_sizes, int n_in,
                              void* d_out, int out_size, void* d_ws, size_t ws_size,
                              hipStream_t stream) {
  const float* x      = (const float*)d_in[0];
  const float* dbz    = (const float*)d_in[1];
  const float* qkv_w  = (const float*)d_in[2];
  const float* proj_w = (const float*)d_in[3];
  const float* proj_b = (const float*)d_in[4];
  float* out = (float*)d_out;

  char* w = (char*)d_ws;
  __bf16* xb     = (__bf16*)(w);                        // 2 MB
  __bf16* qb     = (__bf16*)(w + (2u << 20));           // 2 MB
  __bf16* kb     = (__bf16*)(w + (4u << 20));           // 2 MB
  __bf16* vt     = (__bf16*)(w + (6u << 20));           // 8*32*4128*2 = 2.02 MB
  __bf16* ob     = (__bf16*)(w + (8u << 20) + (256u << 10));  // 2 MB @ 8.25MB
  __bf16* wqkvb  = (__bf16*)(w + (10u << 20) + (512u << 10)); // 384 KB @ 10.5MB
  __bf16* wprojb = (__bf16*)(w + (11u << 20));          // 128 KB
  float*  bias   = (float*)(w + (11u << 20) + 262144);  // 16 KB
  int*    keepi  = (int*)(w + (11u << 20) + 262144 + 16384);  // 16 KB
  float*  o_part = (float*)(w + (12u << 20));           // 8 MB (2x8x4096x32 f32)
  float*  l_part = (float*)(w + (20u << 20));           // 256 KB

  prep_mask<<<dim3(16), dim3(256), 0, stream>>>(dbz, bias, keepi);
  cvt_bf16<<<dim3((N_TOK * CDIM + 255) / 256), dim3(256), 0, stream>>>(
      x, xb, N_TOK * CDIM, 0, 1.0f);
  cvt_bf16<<<dim3((QKV_N * CDIM + 255) / 256), dim3(256), 0, stream>>>(
      qkv_w, wqkvb, QKV_N * CDIM, CDIM * CDIM, SCALE_F);  // scale Q rows
  cvt_bf16<<<dim3((CDIM * CDIM + 255) / 256), dim3(256), 0, stream>>>(
      proj_w, wprojb, CDIM * CDIM, 0, 1.0f);

  qkv_gemm<<<dim3(N_TOK / 64, QKV_N / 64), dim3(256), 0, stream>>>(
      xb, wqkvb, qb, kb, vt);
  attn_kernel<<<dim3(N_TOK / 64, NH, KSPLIT), dim3(256), 0, stream>>>(
      qb, kb, vt, bias, o_part, l_part);
  attn_combine<<<dim3(NH * N_TOK * HD / 256), dim3(256), 0, stream>>>(
      o_part, l_part, ob);
  proj_gemm<<<dim3(N_TOK / 64, CDIM / 64), dim3(256), 0, stream>>>(
      ob, wprojb, proj_b, keepi, x, out);
}

// Round 5
// 148.497 us; speedup vs baseline: 1.7483x; 1.0344x over previous
//
#include <hip/hip_runtime.h>
#include <hip/hip_bf16.h>

#define N_TOK 4096
#define NH 8
#define HD 32
#define CDIM 256
#define QKV_N 768
#define KSPLIT 2
#define VT_STRIDE 4128              // padded global V^T row: breaks 8192B channel/set alias
#define SCALE_F 0.17677669529663687f
#define LOG2E   1.4426950408889634f

typedef float  f32x4  __attribute__((ext_vector_type(4)));
typedef int    i32x4  __attribute__((ext_vector_type(4)));
typedef short  s16x4  __attribute__((ext_vector_type(4)));
typedef __bf16 bf16x8 __attribute__((ext_vector_type(8)));

union FragI { i32x4 i; bf16x8 b; };
union FragH { struct { s16x4 lo, hi; } s; bf16x8 b; };
union Pack2 { i32x4 i; s16x4 h[2]; };

// ---------------------------------------------------------------------------
// fused prep: x->bf16, qkv_w->bf16 (Q rows pre-scaled by SCALE*log2e for the
// exp2 softmax), proj_w->bf16, keep-mask (3x3 dilation of dbz>=15) -> bias/keepi
#define SEG_X 1048576
#define SEG_W (SEG_X + 196608)
#define SEG_P (SEG_W + 65536)
#define SEG_M (SEG_P + 4096)
__global__ __launch_bounds__(256) void fused_prep(const float* __restrict__ x,
                                                  const float* __restrict__ qkv_w,
                                                  const float* __restrict__ proj_w,
                                                  const float* __restrict__ dbz,
                                                  __bf16* __restrict__ xb,
                                                  __bf16* __restrict__ wqkvb,
                                                  __bf16* __restrict__ wprojb,
                                                  float* __restrict__ bias,
                                                  int* __restrict__ keepi) {
  int gid = blockIdx.x * 256 + threadIdx.x;
  if (gid < SEG_X) {
    xb[gid] = (__bf16)x[gid];
  } else if (gid < SEG_W) {
    int i = gid - SEG_X;
    float s = ((i >> 8) < 256) ? (SCALE_F * LOG2E) : 1.0f;   // Q output rows
    wqkvb[i] = (__bf16)(qkv_w[i] * s);
  } else if (gid < SEG_P) {
    int i = gid - SEG_W;
    wprojb[i] = (__bf16)proj_w[i];
  } else if (gid < SEG_M) {
    int n = gid - SEG_P;
    int t = n >> 10, rc = n & 1023, r = rc >> 5, c = rc & 31;
    bool keep = false;
    #pragma unroll
    for (int dr = -1; dr <= 1; dr++)
      #pragma unroll
      for (int dc = -1; dc <= 1; dc++) {
        int rr = r + dr, cc = c + dc;
        if (rr >= 0 && rr < 32 && cc >= 0 && cc < 32)
          keep = keep || (dbz[t * 1024 + rr * 32 + cc] >= 15.0f);
      }
    bias[n]  = keep ? 0.0f : -30000.0f;   // exp2(s-30000) == 0 exactly
    keepi[n] = keep ? 1 : 0;
  }
}

// ---------------------------------------------------------------------------
// QKV GEMM, operand-swapped: D[channel][token] so stores are vectorized.
// q,k -> [h][n][d] (8B stores); v -> [h][d][VT_STRIDE] (32B m-contiguous segs)
__global__ __launch_bounds__(256) void qkv_gemm(const __bf16* __restrict__ xb,
                                                const __bf16* __restrict__ wb,
                                                __bf16* __restrict__ qb,
                                                __bf16* __restrict__ kb,
                                                __bf16* __restrict__ vt) {
  int wave = threadIdx.x >> 6, lane = threadIdx.x & 63;
  int quad = lane >> 4, l16 = lane & 15;
  int m0 = blockIdx.x * 64 + wave * 16;   // tokens
  int n0 = blockIdx.y * 64;               // output channels

  f32x4 acc[4] = {};
  for (int kk = 0; kk < CDIM; kk += 32) {
    FragI xf;   // B operand: col = token = l16
    xf.i = *(const i32x4*)(xb + (size_t)(m0 + l16) * CDIM + kk + quad * 8);
    #pragma unroll
    for (int nt = 0; nt < 4; nt++) {
      FragI wf;  // A operand: row = channel = l16
      wf.i = *(const i32x4*)(wb + (size_t)(n0 + nt * 16 + l16) * CDIM + kk + quad * 8);
      acc[nt] = __builtin_amdgcn_mfma_f32_16x16x32_bf16(wf.b, xf.b, acc[nt], 0, 0, 0);
    }
  }
  int m = m0 + l16;
  #pragma unroll
  for (int nt = 0; nt < 4; nt++) {
    int cbase = n0 + nt * 16 + quad * 4;       // 4 consecutive channels
    int which = cbase >> 8, rem = cbase & 255, hd = rem >> 5, d0 = rem & 31;
    if (which < 2) {
      union { s16x4 s; __bf16 h[4]; } u;
      #pragma unroll
      for (int r = 0; r < 4; r++) u.h[r] = (__bf16)acc[nt][r];
      __bf16* dst = (which == 0 ? qb : kb) + ((size_t)hd * N_TOK + m) * HD + d0;
      *(s16x4*)dst = u.s;
    } else {
      #pragma unroll
      for (int r = 0; r < 4; r++)
        vt[(size_t)(hd * HD + d0 + r) * VT_STRIDE + m] = (__bf16)acc[nt][r];
    }
  }
}

// ---------------------------------------------------------------------------
// Attention v4. One wave = 16 queries x 2048 keys (KSPLIT=2). Inner loop has
// near-zero scalar VALU: bias preloaded into the S-MFMA C operand (global,
// L1-hot broadcast); exp2 native; l via ones-MFMA; K & V double-buffered in
// LDS with immediate-offset frag reads. V LDS rows padded to 140 elems
// (70 words, odd spread -> conflict-free uniform-2). 33.5 KB LDS -> 4 blk/CU.
__global__ __launch_bounds__(256, 4) void attn_kernel(const __bf16* __restrict__ qb,
                                                      const __bf16* __restrict__ kb,
                                                      const __bf16* __restrict__ vt,
                                                      const float* __restrict__ bias,
                                                      float* __restrict__ o_part,
                                                      float* __restrict__ l_part) {
  __shared__ __align__(16) char smem[16384 + 17920];  // K 2x8KB | V 2x8.75KB

  int b = blockIdx.x;
  int head = b & 7, qx = (b >> 3) & 63, ks = b >> 9;  // head = b%8 -> XCD affinity
  int wave = threadIdx.x >> 6, lane = threadIdx.x & 63;
  int quad = lane >> 4, l16 = lane & 15;
  int q0 = qx * 64 + wave * 16;
  int kbeg = ks * (N_TOK / KSPLIT);

  const __bf16* qh = qb + (size_t)head * N_TOK * HD;
  const __bf16* kh = kb + (size_t)head * N_TOK * HD;
  const __bf16* vh = vt + (size_t)head * HD * VT_STRIDE;

  FragI qf;
  qf.i = *(const i32x4*)(qh + (size_t)(q0 + l16) * HD + quad * 8);

  FragI ones;
  #pragma unroll
  for (int j = 0; j < 8; j++) ones.b[j] = (__bf16)1.0f;

  // staging geometry
  int vd = threadIdx.x >> 3;             // V row (d) 0..31
  int vk = (threadIdx.x & 7) * 16;       // V key offset 0..112
  char* kt = smem;                        // [2][128][32] bf16, linear
  char* vtl = smem + 16384;               // [2][32][140] bf16, padded rows

  // stage tile 0 into buf 0
  {
    const char* ks0 = (const char*)(kh + (size_t)kbeg * HD) + threadIdx.x * 32;
    i32x4 k0a = *(const i32x4*)(ks0);
    i32x4 k0b = *(const i32x4*)(ks0 + 16);
    const __bf16* vs0 = vh + (size_t)vd * VT_STRIDE + kbeg + vk;
    Pack2 v0a, v0b;
    v0a.i = *(const i32x4*)(vs0);
    v0b.i = *(const i32x4*)(vs0 + 8);
    char* kd = kt + threadIdx.x * 32;
    *(i32x4*)kd = k0a; *(i32x4*)(kd + 16) = k0b;
    __bf16* vdst = (__bf16*)(vtl) + vd * 140 + vk;
    *(s16x4*)(vdst + 0)  = v0a.h[0]; *(s16x4*)(vdst + 4)  = v0a.h[1];
    *(s16x4*)(vdst + 8)  = v0b.h[0]; *(s16x4*)(vdst + 12) = v0b.h[1];
  }
  __syncthreads();

  f32x4 o_lo = {0.f, 0.f, 0.f, 0.f}, o_hi = {0.f, 0.f, 0.f, 0.f};
  f32x4 lacc = {0.f, 0.f, 0.f, 0.f};

  const char* kbase = kt + l16 * 64 + quad * 16;
  const char* vbase = vtl + l16 * 280 + quad * 8;

  for (int t2 = 0; t2 < 8; t2++) {
    #pragma unroll
    for (int half = 0; half < 2; half++) {
      int tile = t2 * 2 + half;
      int nbuf = half ^ 1;
      bool pre = (tile < 15);

      i32x4 kp0, kp1; Pack2 vp0, vp1;
      if (pre) {
        const char* ksn = (const char*)(kh + (size_t)(kbeg + (tile + 1) * 128) * HD)
                          + threadIdx.x * 32;
        kp0 = *(const i32x4*)(ksn);
        kp1 = *(const i32x4*)(ksn + 16);
        const __bf16* vsn = vh + (size_t)vd * VT_STRIDE + kbeg + (tile + 1) * 128 + vk;
        vp0.i = *(const i32x4*)(vsn);
        vp1.i = *(const i32x4*)(vsn + 8);
      }

      #pragma unroll
      for (int step = 0; step < 4; step++) {
        int k0 = kbeg + tile * 128 + step * 32;

        FragI ka, kb2;
        ka.i  = *(const i32x4*)(kbase + half * 8192 + step * 2048);
        kb2.i = *(const i32x4*)(kbase + half * 8192 + step * 2048 + 1024);

        f32x4 ba = *(const f32x4*)(bias + k0 + quad * 4);
        f32x4 bb = *(const f32x4*)(bias + k0 + 16 + quad * 4);

        // S^T = K*Q^T with C initialized to bias(key): D[key][q] (+bias)
        f32x4 sa = __builtin_amdgcn_mfma_f32_16x16x32_bf16(ka.b,  qf.b, ba, 0, 0, 0);
        f32x4 sb = __builtin_amdgcn_mfma_f32_16x16x32_bf16(kb2.b, qf.b, bb, 0, 0, 0);

        FragI pf;
        #pragma unroll
        for (int r = 0; r < 4; r++) {
          pf.b[r]     = (__bf16)exp2f(sa[r]);   // native v_exp_f32
          pf.b[4 + r] = (__bf16)exp2f(sb[r]);
        }

        FragH vlo, vhi;
        vlo.s.lo = *(const s16x4*)(vbase + half * 8960 + step * 64);
        vlo.s.hi = *(const s16x4*)(vbase + half * 8960 + step * 64 + 32);
        vhi.s.lo = *(const s16x4*)(vbase + half * 8960 + step * 64 + 4480);
        vhi.s.hi = *(const s16x4*)(vbase + half * 8960 + step * 64 + 4480 + 32);

        o_lo = __builtin_amdgcn_mfma_f32_16x16x32_bf16(vlo.b, pf.b, o_lo, 0, 0, 0);
        o_hi = __builtin_amdgcn_mfma_f32_16x16x32_bf16(vhi.b, pf.b, o_hi, 0, 0, 0);
        lacc = __builtin_amdgcn_mfma_f32_16x16x32_bf16(ones.b, pf.b, lacc, 0, 0, 0);
      }

      if (pre) {
        char* kd = kt + nbuf * 8192 + threadIdx.x * 32;
        *(i32x4*)kd = kp0; *(i32x4*)(kd + 16) = kp1;
        __bf16* vdst = (__bf16*)(vtl) + nbuf * 4480 + vd * 140 + vk;
        *(s16x4*)(vdst + 0)  = vp0.h[0]; *(s16x4*)(vdst + 4)  = vp0.h[1];
        *(s16x4*)(vdst + 8)  = vp1.h[0]; *(s16x4*)(vdst + 12) = vp1.h[1];
      }
      __syncthreads();
    }
  }

  // O^T: o_lo[r] = O[q=l16][d=quad*4+r], o_hi -> d+16 (unnormalized partials)
  float* op = o_part + ((size_t)(ks * NH + head) * N_TOK + q0 + l16) * HD;
  *(f32x4*)(op + quad * 4)      = o_lo;
  *(f32x4*)(op + 16 + quad * 4) = o_hi;
  if (quad == 0)   // lacc rows all equal sum_k P[k][q=l16]
    l_part[(size_t)(ks * NH + head) * N_TOK + q0 + l16] = lacc[0];
}

// ---------------------------------------------------------------------------
// Combine split-K partials: ob[q, h*32+d] = (o0+o1) / (l0+l1)   (bf16)
__global__ __launch_bounds__(256) void attn_combine(const float* __restrict__ o_part,
                                                    const float* __restrict__ l_part,
                                                    __bf16* __restrict__ ob) {
  int idx = blockIdx.x * 256 + threadIdx.x;
  int d = idx & 31, q = (idx >> 5) & (N_TOK - 1), h = idx >> 17;
  float o0 = o_part[((size_t)h * N_TOK + q) * HD + d];
  float o1 = o_part[((size_t)(NH + h) * N_TOK + q) * HD + d];
  float l0 = l_part[(size_t)h * N_TOK + q];
  float l1 = l_part[(size_t)(NH + h) * N_TOK + q];
  ob[(size_t)q * CDIM + h * HD + d] = (__bf16)((o0 + o1) / (l0 + l1));
}

// ---------------------------------------------------------------------------
// Output projection: out = (keep ? attn@Wp^T + b : 0) + x   (fp32 out)
__global__ __launch_bounds__(256) void proj_gemm(const __bf16* __restrict__ ob,
                                                 const __bf16* __restrict__ wb,
                                                 const float* __restrict__ pb,
                                                 const int* __restrict__ keepi,
                                                 const float* __restrict__ x,
                                                 float* __restrict__ out) {
  int wave = threadIdx.x >> 6, lane = threadIdx.x & 63;
  int quad = lane >> 4, l16 = lane & 15;
  int m0 = blockIdx.x * 64 + wave * 16;
  int n0 = blockIdx.y * 64;

  f32x4 acc[4] = {};
  for (int kk = 0; kk < CDIM; kk += 32) {
    FragI af;
    af.i = *(const i32x4*)(ob + (size_t)(m0 + l16) * CDIM + kk + quad * 8);
    #pragma unroll
    for (int nt = 0; nt < 4; nt++) {
      FragI bfr;
      bfr.i = *(const i32x4*)(wb + (size_t)(n0 + nt * 16 + l16) * CDIM + kk + quad * 8);
      acc[nt] = __builtin_amdgcn_mfma_f32_16x16x32_bf16(af.b, bfr.b, acc[nt], 0, 0, 0);
    }
  }
  #pragma unroll
  for (int nt = 0; nt < 4; nt++) {
    int c = n0 + nt * 16 + l16;
    #pragma unroll
    for (int r = 0; r < 4; r++) {
      int m = m0 + quad * 4 + r;
      float v = acc[nt][r] + pb[c];
      v = keepi[m] ? v : 0.0f;
      out[(size_t)m * CDIM + c] = v + x[(size_t)m * CDIM + c];
    }
  }
}

// ---------------------------------------------------------------------------
extern "C" void kernel_launch(void* const* d_in, const int* in_sizes, int n_in,
                              void* d_out, int out_size, void* d_ws, size_t ws_size,
                              hipStream_t stream) {
  const float* x      = (const float*)d_in[0];
  const float* dbz    = (const float*)d_in[1];
  const float* qkv_w  = (const float*)d_in[2];
  const float* proj_w = (const float*)d_in[3];
  const float* proj_b = (const float*)d_in[4];
  float* out = (float*)d_out;

  char* w = (char*)d_ws;
  __bf16* xb     = (__bf16*)(w);                        // 2 MB
  __bf16* qb     = (__bf16*)(w + (2u << 20));           // 2 MB
  __bf16* kb     = (__bf16*)(w + (4u << 20));           // 2 MB
  __bf16* vt     = (__bf16*)(w + (6u << 20));           // 8*32*4128*2 = 2.02 MB
  __bf16* ob     = (__bf16*)(w + (8u << 20) + (256u << 10));  // 2 MB
  __bf16* wqkvb  = (__bf16*)(w + (10u << 20) + (512u << 10)); // 384 KB
  __bf16* wprojb = (__bf16*)(w + (11u << 20));          // 128 KB
  float*  bias   = (float*)(w + (11u << 20) + 262144);  // 16 KB
  int*    keepi  = (int*)(w + (11u << 20) + 262144 + 16384);  // 16 KB
  float*  o_part = (float*)(w + (12u << 20));           // 8 MB
  float*  l_part = (float*)(w + (20u << 20));           // 256 KB

  fused_prep<<<dim3(SEG_M / 256), dim3(256), 0, stream>>>(
      x, qkv_w, proj_w, dbz, xb, wqkvb, wprojb, bias, keepi);
  qkv_gemm<<<dim3(N_TOK / 64, QKV_N / 64), dim3(256), 0, stream>>>(
      xb, wqkvb, qb, kb, vt);
  attn_kernel<<<dim3((N_TOK / 64) * NH * KSPLIT), dim3(256), 0, stream>>>(
      qb, kb, vt, bias, o_part, l_part);
  attn_combine<<<dim3(NH * N_TOK * HD / 256), dim3(256), 0, stream>>>(
      o_part, l_part, ob);
  proj_gemm<<<dim3(N_TOK / 64, CDIM / 64), dim3(256), 0, stream>>>(
      ob, wprojb, proj_b, keepi, x, out);
}

// Round 6
// 127.496 us; speedup vs baseline: 2.0363x; 1.1647x over previous
//
#include <hip/hip_runtime.h>
#include <hip/hip_bf16.h>

#define N_TOK 4096
#define NH 8
#define HD 32
#define CDIM 256
#define QKV_N 768
#define VT_STRIDE 4128   // padded global V^T row: breaks power-of-2 channel/set alias
#define XB_STRIDE 272    // padded rows for xb/ob/weight scratch (breaks 512B stride)
#define SCALE_F 0.17677669529663687f
#define LOG2E   1.4426950408889634f

typedef float  f32x4  __attribute__((ext_vector_type(4)));
typedef int    i32x4  __attribute__((ext_vector_type(4)));
typedef short  s16x4  __attribute__((ext_vector_type(4)));
typedef __bf16 bf16x8 __attribute__((ext_vector_type(8)));

union FragI { i32x4 i; bf16x8 b; };
union FragH { struct { s16x4 lo, hi; } s; bf16x8 b; };

// ---------------------------------------------------------------------------
// fused prep: x->bf16 (rows padded to 272), qkv_w->bf16 (Q rows pre-scaled by
// SCALE*log2e), proj_w->bf16, keep-mask -> bias/keepi.
#define SEG_X 1048576
#define SEG_W (SEG_X + 196608)
#define SEG_P (SEG_W + 65536)
#define SEG_M (SEG_P + 4096)
__global__ __launch_bounds__(256) void fused_prep(const float* __restrict__ x,
                                                  const float* __restrict__ qkv_w,
                                                  const float* __restrict__ proj_w,
                                                  const float* __restrict__ dbz,
                                                  __bf16* __restrict__ xb,
                                                  __bf16* __restrict__ wqkvb,
                                                  __bf16* __restrict__ wprojb,
                                                  float* __restrict__ bias,
                                                  int* __restrict__ keepi) {
  int gid = blockIdx.x * 256 + threadIdx.x;
  if (gid < SEG_X) {
    xb[(gid >> 8) * XB_STRIDE + (gid & 255)] = (__bf16)x[gid];
  } else if (gid < SEG_W) {
    int i = gid - SEG_X;
    float s = ((i >> 8) < 256) ? (SCALE_F * LOG2E) : 1.0f;   // Q output rows
    wqkvb[(i >> 8) * XB_STRIDE + (i & 255)] = (__bf16)(qkv_w[i] * s);
  } else if (gid < SEG_P) {
    int i = gid - SEG_W;
    wprojb[(i >> 8) * XB_STRIDE + (i & 255)] = (__bf16)proj_w[i];
  } else if (gid < SEG_M) {
    int n = gid - SEG_P;
    int t = n >> 10, rc = n & 1023, r = rc >> 5, c = rc & 31;
    bool keep = false;
    #pragma unroll
    for (int dr = -1; dr <= 1; dr++)
      #pragma unroll
      for (int dc = -1; dc <= 1; dc++) {
        int rr = r + dr, cc = c + dc;
        if (rr >= 0 && rr < 32 && cc >= 0 && cc < 32)
          keep = keep || (dbz[t * 1024 + rr * 32 + cc] >= 15.0f);
      }
    bias[n]  = keep ? 0.0f : -30000.0f;   // exp2(s-30000) == 0 exactly
    keepi[n] = keep ? 1 : 0;
  }
}

// ---------------------------------------------------------------------------
// QKV GEMM, operand-swapped (D[channel][token]), software-pipelined k-loop.
// q,k -> [h][n][d] (8B stores); v -> [h][d][VT_STRIDE].
__global__ __launch_bounds__(256) void qkv_gemm(const __bf16* __restrict__ xb,
                                                const __bf16* __restrict__ wb,
                                                __bf16* __restrict__ qb,
                                                __bf16* __restrict__ kb,
                                                __bf16* __restrict__ vt) {
  int wave = threadIdx.x >> 6, lane = threadIdx.x & 63;
  int quad = lane >> 4, l16 = lane & 15;
  int m0 = blockIdx.x * 64 + wave * 16;   // tokens
  int n0 = blockIdx.y * 64;               // output channels

  const __bf16* xrow = xb + (size_t)(m0 + l16) * XB_STRIDE + quad * 8;
  const __bf16* wrow = wb + (size_t)(n0 + l16) * XB_STRIDE + quad * 8;

  FragI xc, wc[4];
  xc.i = *(const i32x4*)(xrow);
  #pragma unroll
  for (int nt = 0; nt < 4; nt++)
    wc[nt].i = *(const i32x4*)(wrow + (size_t)nt * 16 * XB_STRIDE);

  f32x4 acc[4] = {};
  for (int kk = 0; kk < CDIM; kk += 32) {
    int kn = (kk + 32 < CDIM) ? kk + 32 : 0;      // last prefetch unused
    FragI xn, wn[4];
    xn.i = *(const i32x4*)(xrow + kn);
    #pragma unroll
    for (int nt = 0; nt < 4; nt++)
      wn[nt].i = *(const i32x4*)(wrow + (size_t)nt * 16 * XB_STRIDE + kn);
    #pragma unroll
    for (int nt = 0; nt < 4; nt++)
      acc[nt] = __builtin_amdgcn_mfma_f32_16x16x32_bf16(wc[nt].b, xc.b, acc[nt], 0, 0, 0);
    xc = xn;
    #pragma unroll
    for (int nt = 0; nt < 4; nt++) wc[nt] = wn[nt];
  }
  int m = m0 + l16;
  #pragma unroll
  for (int nt = 0; nt < 4; nt++) {
    int cbase = n0 + nt * 16 + quad * 4;       // 4 consecutive channels
    int which = cbase >> 8, rem = cbase & 255, hd = rem >> 5, d0 = rem & 31;
    if (which < 2) {
      union { s16x4 s; __bf16 h[4]; } u;
      #pragma unroll
      for (int r = 0; r < 4; r++) u.h[r] = (__bf16)acc[nt][r];
      __bf16* dst = (which == 0 ? qb : kb) + ((size_t)hd * N_TOK + m) * HD + d0;
      *(s16x4*)dst = u.s;
    } else {
      #pragma unroll
      for (int r = 0; r < 4; r++)
        vt[(size_t)(hd * HD + d0 + r) * VT_STRIDE + m] = (__bf16)acc[nt][r];
    }
  }
}

// ---------------------------------------------------------------------------
// Attention v5: waves split KEYS, not queries. Block = 64 queries x 1 head;
// wave w owns key stripe {w*32 + 128*t}. Q register-stationary (4 frags);
// K/V wave-private from global (K rows 1KB-contiguous; V via padded
// VT_STRIDE) -> NO LDS, NO barriers, NO redundancy in the 32-step loop.
// Softmax: no-max exp2 (scores O(1); masked keys exp2(s-30000)==0); bias in
// the S-MFMA C operand; l via ones-MFMA. One LDS round-trip at the end for
// the cross-wave O/l reduction; output normalized + written here (bf16).
__global__ __launch_bounds__(256, 2) void attn_kernel(const __bf16* __restrict__ qb,
                                                      const __bf16* __restrict__ kb,
                                                      const __bf16* __restrict__ vt,
                                                      const float* __restrict__ bias,
                                                      __bf16* __restrict__ ob) {
  __shared__ float red_o[4][64][34];   // stride 34 words: 8B-aligned, 4-way max
  __shared__ float red_l[4][64];

  int b = blockIdx.x;
  int head = b & 7, qx = b >> 3;       // 512 blocks = 2/CU exactly
  int wave = threadIdx.x >> 6, lane = threadIdx.x & 63;
  int quad = lane >> 4, l16 = lane & 15;
  int q0 = qx * 64;

  const __bf16* qh = qb + (size_t)head * N_TOK * HD;
  const __bf16* kh = kb + (size_t)head * N_TOK * HD;
  const __bf16* vh = vt + (size_t)head * HD * VT_STRIDE;

  FragI qf[4];
  #pragma unroll
  for (int g = 0; g < 4; g++)
    qf[g].i = *(const i32x4*)(qh + (size_t)(q0 + g * 16 + l16) * HD + quad * 8);

  FragI ones;
  #pragma unroll
  for (int j = 0; j < 8; j++) ones.b[j] = (__bf16)1.0f;

  f32x4 o_lo[4] = {}, o_hi[4] = {}, lacc[4] = {};

  // rolling K/bias prefetch (V issued early inside the step; used after exp)
  FragI ka_c, kb_c;
  f32x4 ba_c, bb_c;
  {
    int k0 = wave * 32;
    ka_c.i = *(const i32x4*)(kh + (size_t)(k0 + l16) * HD + quad * 8);
    kb_c.i = *(const i32x4*)(kh + (size_t)(k0 + 16 + l16) * HD + quad * 8);
    ba_c = *(const f32x4*)(bias + k0 + quad * 4);
    bb_c = *(const f32x4*)(bias + k0 + 16 + quad * 4);
  }

  for (int t = 0; t < 32; t++) {
    int kc = wave * 32 + t * 128;
    int kn = (t < 31) ? kc + 128 : wave * 32;   // wrap: last prefetch unused

    FragI ka_n, kb_n;
    f32x4 ba_n, bb_n;
    ka_n.i = *(const i32x4*)(kh + (size_t)(kn + l16) * HD + quad * 8);
    kb_n.i = *(const i32x4*)(kh + (size_t)(kn + 16 + l16) * HD + quad * 8);
    ba_n = *(const f32x4*)(bias + kn + quad * 4);
    bb_n = *(const f32x4*)(bias + kn + 16 + quad * 4);

    // V frags for current keys (pi-ordered), issued before the S-MFMAs
    FragH vlo, vhi;
    const __bf16* vp = vh + (size_t)l16 * VT_STRIDE + kc + quad * 4;
    vlo.s.lo = *(const s16x4*)(vp);
    vlo.s.hi = *(const s16x4*)(vp + 16);
    const __bf16* vp2 = vh + (size_t)(16 + l16) * VT_STRIDE + kc + quad * 4;
    vhi.s.lo = *(const s16x4*)(vp2);
    vhi.s.hi = *(const s16x4*)(vp2 + 16);

    // S^T per q-group: D[key][q] init = bias(key)
    f32x4 sa[4], sb[4];
    #pragma unroll
    for (int g = 0; g < 4; g++) {
      sa[g] = __builtin_amdgcn_mfma_f32_16x16x32_bf16(ka_c.b, qf[g].b, ba_c, 0, 0, 0);
      sb[g] = __builtin_amdgcn_mfma_f32_16x16x32_bf16(kb_c.b, qf[g].b, bb_c, 0, 0, 0);
    }

    FragI pf[4];
    #pragma unroll
    for (int g = 0; g < 4; g++) {
      #pragma unroll
      for (int r = 0; r < 4; r++) {
        pf[g].b[r]     = (__bf16)exp2f(sa[g][r]);   // native v_exp_f32
        pf[g].b[4 + r] = (__bf16)exp2f(sb[g][r]);
      }
    }

    #pragma unroll
    for (int g = 0; g < 4; g++) {
      o_lo[g] = __builtin_amdgcn_mfma_f32_16x16x32_bf16(vlo.b, pf[g].b, o_lo[g], 0, 0, 0);
      o_hi[g] = __builtin_amdgcn_mfma_f32_16x16x32_bf16(vhi.b, pf[g].b, o_hi[g], 0, 0, 0);
      lacc[g] = __builtin_amdgcn_mfma_f32_16x16x32_bf16(ones.b, pf[g].b, lacc[g], 0, 0, 0);
    }

    ka_c = ka_n; kb_c = kb_n; ba_c = ba_n; bb_c = bb_n;
  }

  // ---- cross-wave reduction (one LDS round-trip) ----
  #pragma unroll
  for (int g = 0; g < 4; g++) {
    int q = g * 16 + l16;
    #pragma unroll
    for (int r = 0; r < 4; r++) {
      red_o[wave][q][quad * 4 + r]      = o_lo[g][r];
      red_o[wave][q][16 + quad * 4 + r] = o_hi[g][r];
    }
    if (quad == 0) red_l[wave][q] = lacc[g][0];  // all rows equal = l(q)
  }
  __syncthreads();

  // wave w reduces q-group g = w
  int q = wave * 16 + l16;
  float lt = red_l[0][q] + red_l[1][q] + red_l[2][q] + red_l[3][q];
  float inv = 1.0f / lt;
  f32x4 slo = {0.f, 0.f, 0.f, 0.f}, shi = {0.f, 0.f, 0.f, 0.f};
  #pragma unroll
  for (int src = 0; src < 4; src++) {
    #pragma unroll
    for (int r = 0; r < 4; r++) {
      slo[r] += red_o[src][q][quad * 4 + r];
      shi[r] += red_o[src][q][16 + quad * 4 + r];
    }
  }
  union { s16x4 s; __bf16 h[4]; } u1, u2;
  #pragma unroll
  for (int r = 0; r < 4; r++) {
    u1.h[r] = (__bf16)(slo[r] * inv);
    u2.h[r] = (__bf16)(shi[r] * inv);
  }
  __bf16* orow = ob + (size_t)(q0 + q) * XB_STRIDE + head * HD;
  *(s16x4*)(orow + quad * 4)      = u1.s;
  *(s16x4*)(orow + 16 + quad * 4) = u2.s;
}

// ---------------------------------------------------------------------------
// Output projection (pipelined): out = (keep ? attn@Wp^T + b : 0) + x
__global__ __launch_bounds__(256) void proj_gemm(const __bf16* __restrict__ ob,
                                                 const __bf16* __restrict__ wb,
                                                 const float* __restrict__ pb,
                                                 const int* __restrict__ keepi,
                                                 const float* __restrict__ x,
                                                 float* __restrict__ out) {
  int wave = threadIdx.x >> 6, lane = threadIdx.x & 63;
  int quad = lane >> 4, l16 = lane & 15;
  int m0 = blockIdx.x * 64 + wave * 16;
  int n0 = blockIdx.y * 64;

  const __bf16* arow = ob + (size_t)(m0 + l16) * XB_STRIDE + quad * 8;
  const __bf16* wrow = wb + (size_t)(n0 + l16) * XB_STRIDE + quad * 8;

  FragI ac, wc[4];
  ac.i = *(const i32x4*)(arow);
  #pragma unroll
  for (int nt = 0; nt < 4; nt++)
    wc[nt].i = *(const i32x4*)(wrow + (size_t)nt * 16 * XB_STRIDE);

  f32x4 acc[4] = {};
  for (int kk = 0; kk < CDIM; kk += 32) {
    int kn = (kk + 32 < CDIM) ? kk + 32 : 0;
    FragI an, wn[4];
    an.i = *(const i32x4*)(arow + kn);
    #pragma unroll
    for (int nt = 0; nt < 4; nt++)
      wn[nt].i = *(const i32x4*)(wrow + (size_t)nt * 16 * XB_STRIDE + kn);
    #pragma unroll
    for (int nt = 0; nt < 4; nt++)
      acc[nt] = __builtin_amdgcn_mfma_f32_16x16x32_bf16(wc[nt].b, ac.b, acc[nt], 0, 0, 0);
    ac = an;
    #pragma unroll
    for (int nt = 0; nt < 4; nt++) wc[nt] = wn[nt];
  }
  // D[channel][token]: row = channel quad*4+r, col = token l16
  int m = m0 + l16;
  int keep = keepi[m];
  #pragma unroll
  for (int nt = 0; nt < 4; nt++) {
    int c0 = n0 + nt * 16 + quad * 4;
    #pragma unroll
    for (int r = 0; r < 4; r++) {
      float v = acc[nt][r] + pb[c0 + r];
      v = keep ? v : 0.0f;
      out[(size_t)m * CDIM + c0 + r] = v + x[(size_t)m * CDIM + c0 + r];
    }
  }
}

// ---------------------------------------------------------------------------
extern "C" void kernel_launch(void* const* d_in, const int* in_sizes, int n_in,
                              void* d_out, int out_size, void* d_ws, size_t ws_size,
                              hipStream_t stream) {
  const float* x      = (const float*)d_in[0];
  const float* dbz    = (const float*)d_in[1];
  const float* qkv_w  = (const float*)d_in[2];
  const float* proj_w = (const float*)d_in[3];
  const float* proj_b = (const float*)d_in[4];
  float* out = (float*)d_out;

  char* w = (char*)d_ws;
  __bf16* xb     = (__bf16*)(w);                        // 4096x272x2 = 2.23MB
  __bf16* qb     = (__bf16*)(w + (3u << 20));           // 2MB
  __bf16* kb     = (__bf16*)(w + (5u << 20));           // 2MB
  __bf16* vt     = (__bf16*)(w + (7u << 20));           // 8*32*4128*2 = 2.02MB
  __bf16* ob     = (__bf16*)(w + (9u << 20) + (512u << 10));  // 2.23MB
  __bf16* wqkvb  = (__bf16*)(w + (12u << 20));          // 768x272x2 = 417KB
  __bf16* wprojb = (__bf16*)(w + (12u << 20) + (512u << 10)); // 139KB
  float*  bias   = (float*)(w + (13u << 20));           // 16KB
  int*    keepi  = (int*)(w + (13u << 20) + 16384);     // 16KB

  fused_prep<<<dim3(SEG_M / 256), dim3(256), 0, stream>>>(
      x, qkv_w, proj_w, dbz, xb, wqkvb, wprojb, bias, keepi);
  qkv_gemm<<<dim3(N_TOK / 64, QKV_N / 64), dim3(256), 0, stream>>>(
      xb, wqkvb, qb, kb, vt);
  attn_kernel<<<dim3((N_TOK / 64) * NH), dim3(256), 0, stream>>>(
      qb, kb, vt, bias, ob);
  proj_gemm<<<dim3(N_TOK / 64, CDIM / 64), dim3(256), 0, stream>>>(
      ob, wprojb, proj_b, keepi, x, out);
}

// Round 7
// 113.681 us; speedup vs baseline: 2.2837x; 1.1215x over previous
//
#include <hip/hip_runtime.h>
#include <hip/hip_bf16.h>

#define N_TOK 4096
#define NH 8
#define HD 32
#define CDIM 256
#define QKV_N 768
#define VT_STRIDE 4128   // padded global V^T row: breaks power-of-2 channel/set alias
#define XB_STRIDE 272    // padded rows for xb/ob/weight scratch (breaks 512B stride)
#define SCALE_F 0.17677669529663687f
#define LOG2E   1.4426950408889634f

typedef float  f32x4  __attribute__((ext_vector_type(4)));
typedef int    i32x4  __attribute__((ext_vector_type(4)));
typedef short  s16x4  __attribute__((ext_vector_type(4)));
typedef __bf16 bf16x8 __attribute__((ext_vector_type(8)));

union FragI { i32x4 i; bf16x8 b; };
union FragH { struct { s16x4 lo, hi; } s; bf16x8 b; };

// pack two f32 into bf16x2 by truncation: ONE v_perm_b32.
// result low half = a (element 0), high half = b.
__device__ inline int pack_bf16_trunc(float a, float b) {
  return (int)__builtin_amdgcn_perm(__builtin_bit_cast(unsigned, b),
                                    __builtin_bit_cast(unsigned, a),
                                    0x07060302u);
}

// ---------------------------------------------------------------------------
// fused prep: x->bf16 (rows padded to 272), qkv_w->bf16 (Q rows pre-scaled by
// SCALE*log2e), proj_w->bf16, keep-mask -> bias/keepi.
#define SEG_X 1048576
#define SEG_W (SEG_X + 196608)
#define SEG_P (SEG_W + 65536)
#define SEG_M (SEG_P + 4096)
__global__ __launch_bounds__(256) void fused_prep(const float* __restrict__ x,
                                                  const float* __restrict__ qkv_w,
                                                  const float* __restrict__ proj_w,
                                                  const float* __restrict__ dbz,
                                                  __bf16* __restrict__ xb,
                                                  __bf16* __restrict__ wqkvb,
                                                  __bf16* __restrict__ wprojb,
                                                  float* __restrict__ bias,
                                                  int* __restrict__ keepi) {
  int gid = blockIdx.x * 256 + threadIdx.x;
  if (gid < SEG_X) {
    xb[(gid >> 8) * XB_STRIDE + (gid & 255)] = (__bf16)x[gid];
  } else if (gid < SEG_W) {
    int i = gid - SEG_X;
    float s = ((i >> 8) < 256) ? (SCALE_F * LOG2E) : 1.0f;   // Q output rows
    wqkvb[(i >> 8) * XB_STRIDE + (i & 255)] = (__bf16)(qkv_w[i] * s);
  } else if (gid < SEG_P) {
    int i = gid - SEG_W;
    wprojb[(i >> 8) * XB_STRIDE + (i & 255)] = (__bf16)proj_w[i];
  } else if (gid < SEG_M) {
    int n = gid - SEG_P;
    int t = n >> 10, rc = n & 1023, r = rc >> 5, c = rc & 31;
    bool keep = false;
    #pragma unroll
    for (int dr = -1; dr <= 1; dr++)
      #pragma unroll
      for (int dc = -1; dc <= 1; dc++) {
        int rr = r + dr, cc = c + dc;
        if (rr >= 0 && rr < 32 && cc >= 0 && cc < 32)
          keep = keep || (dbz[t * 1024 + rr * 32 + cc] >= 15.0f);
      }
    bias[n]  = keep ? 0.0f : -30000.0f;   // exp2(s-30000) == 0 exactly
    keepi[n] = keep ? 1 : 0;
  }
}

// ---------------------------------------------------------------------------
// QKV GEMM, operand-swapped (D[channel][token]), software-pipelined k-loop.
// q,k -> [h][n][d] (8B stores); v -> [h][d][VT_STRIDE].
__global__ __launch_bounds__(256) void qkv_gemm(const __bf16* __restrict__ xb,
                                                const __bf16* __restrict__ wb,
                                                __bf16* __restrict__ qb,
                                                __bf16* __restrict__ kb,
                                                __bf16* __restrict__ vt) {
  int wave = threadIdx.x >> 6, lane = threadIdx.x & 63;
  int quad = lane >> 4, l16 = lane & 15;
  int m0 = blockIdx.x * 64 + wave * 16;   // tokens
  int n0 = blockIdx.y * 64;               // output channels

  const __bf16* xrow = xb + (size_t)(m0 + l16) * XB_STRIDE + quad * 8;
  const __bf16* wrow = wb + (size_t)(n0 + l16) * XB_STRIDE + quad * 8;

  FragI xc, wc[4];
  xc.i = *(const i32x4*)(xrow);
  #pragma unroll
  for (int nt = 0; nt < 4; nt++)
    wc[nt].i = *(const i32x4*)(wrow + (size_t)nt * 16 * XB_STRIDE);

  f32x4 acc[4] = {};
  for (int kk = 0; kk < CDIM; kk += 32) {
    int kn = (kk + 32 < CDIM) ? kk + 32 : 0;      // last prefetch unused
    FragI xn, wn[4];
    xn.i = *(const i32x4*)(xrow + kn);
    #pragma unroll
    for (int nt = 0; nt < 4; nt++)
      wn[nt].i = *(const i32x4*)(wrow + (size_t)nt * 16 * XB_STRIDE + kn);
    #pragma unroll
    for (int nt = 0; nt < 4; nt++)
      acc[nt] = __builtin_amdgcn_mfma_f32_16x16x32_bf16(wc[nt].b, xc.b, acc[nt], 0, 0, 0);
    xc = xn;
    #pragma unroll
    for (int nt = 0; nt < 4; nt++) wc[nt] = wn[nt];
  }
  int m = m0 + l16;
  #pragma unroll
  for (int nt = 0; nt < 4; nt++) {
    int cbase = n0 + nt * 16 + quad * 4;       // 4 consecutive channels
    int which = cbase >> 8, rem = cbase & 255, hd = rem >> 5, d0 = rem & 31;
    if (which < 2) {
      union { s16x4 s; __bf16 h[4]; } u;
      #pragma unroll
      for (int r = 0; r < 4; r++) u.h[r] = (__bf16)acc[nt][r];
      __bf16* dst = (which == 0 ? qb : kb) + ((size_t)hd * N_TOK + m) * HD + d0;
      *(s16x4*)dst = u.s;
    } else {
      #pragma unroll
      for (int r = 0; r < 4; r++)
        vt[(size_t)(hd * HD + d0 + r) * VT_STRIDE + m] = (__bf16)acc[nt][r];
    }
  }
}

// ---------------------------------------------------------------------------
// Attention v6: waves split KEYS (wave-private K/V, no LDS/barriers in loop,
// Q register-stationary). Softmax: no-max exp2 via __builtin_amdgcn_exp2f
// (single v_exp_f32; masked keys exp2(s-30000)==0), bias in the S-MFMA C
// operand, l via ones-MFMA, P packed to bf16 by TRUNCATION with one
// v_perm_b32 per pair (l computed from the same truncated P -> bias cancels).
__global__ __launch_bounds__(256, 2) void attn_kernel(const __bf16* __restrict__ qb,
                                                      const __bf16* __restrict__ kb,
                                                      const __bf16* __restrict__ vt,
                                                      const float* __restrict__ bias,
                                                      __bf16* __restrict__ ob) {
  __shared__ float red_o[4][64][34];   // stride 34 words: 8B-aligned, 4-way max
  __shared__ float red_l[4][64];

  int b = blockIdx.x;
  int head = b & 7, qx = b >> 3;       // 512 blocks = 2/CU exactly
  int wave = threadIdx.x >> 6, lane = threadIdx.x & 63;
  int quad = lane >> 4, l16 = lane & 15;
  int q0 = qx * 64;

  const __bf16* qh = qb + (size_t)head * N_TOK * HD;
  const __bf16* kh = kb + (size_t)head * N_TOK * HD;
  const __bf16* vh = vt + (size_t)head * HD * VT_STRIDE;

  FragI qf[4];
  #pragma unroll
  for (int g = 0; g < 4; g++)
    qf[g].i = *(const i32x4*)(qh + (size_t)(q0 + g * 16 + l16) * HD + quad * 8);

  FragI ones;
  #pragma unroll
  for (int j = 0; j < 8; j++) ones.b[j] = (__bf16)1.0f;

  f32x4 o_lo[4] = {}, o_hi[4] = {}, lacc[4] = {};

  // rolling K/bias prefetch (V issued early inside the step; used after exp)
  FragI ka_c, kb_c;
  f32x4 ba_c, bb_c;
  {
    int k0 = wave * 32;
    ka_c.i = *(const i32x4*)(kh + (size_t)(k0 + l16) * HD + quad * 8);
    kb_c.i = *(const i32x4*)(kh + (size_t)(k0 + 16 + l16) * HD + quad * 8);
    ba_c = *(const f32x4*)(bias + k0 + quad * 4);
    bb_c = *(const f32x4*)(bias + k0 + 16 + quad * 4);
  }

  for (int t = 0; t < 32; t++) {
    int kc = wave * 32 + t * 128;
    int kn = (t < 31) ? kc + 128 : wave * 32;   // wrap: last prefetch unused

    FragI ka_n, kb_n;
    f32x4 ba_n, bb_n;
    ka_n.i = *(const i32x4*)(kh + (size_t)(kn + l16) * HD + quad * 8);
    kb_n.i = *(const i32x4*)(kh + (size_t)(kn + 16 + l16) * HD + quad * 8);
    ba_n = *(const f32x4*)(bias + kn + quad * 4);
    bb_n = *(const f32x4*)(bias + kn + 16 + quad * 4);

    // V frags for current keys (pi-ordered), issued before the S-MFMAs
    FragH vlo, vhi;
    const __bf16* vp = vh + (size_t)l16 * VT_STRIDE + kc + quad * 4;
    vlo.s.lo = *(const s16x4*)(vp);
    vlo.s.hi = *(const s16x4*)(vp + 16);
    const __bf16* vp2 = vh + (size_t)(16 + l16) * VT_STRIDE + kc + quad * 4;
    vhi.s.lo = *(const s16x4*)(vp2);
    vhi.s.hi = *(const s16x4*)(vp2 + 16);

    // S^T per q-group: D[key][q] init = bias(key)
    f32x4 sa[4], sb[4];
    #pragma unroll
    for (int g = 0; g < 4; g++) {
      sa[g] = __builtin_amdgcn_mfma_f32_16x16x32_bf16(ka_c.b, qf[g].b, ba_c, 0, 0, 0);
      sb[g] = __builtin_amdgcn_mfma_f32_16x16x32_bf16(kb_c.b, qf[g].b, bb_c, 0, 0, 0);
    }

    FragI pf[4];
    #pragma unroll
    for (int g = 0; g < 4; g++) {
      float e0 = __builtin_amdgcn_exp2f(sa[g][0]);
      float e1 = __builtin_amdgcn_exp2f(sa[g][1]);
      float e2 = __builtin_amdgcn_exp2f(sa[g][2]);
      float e3 = __builtin_amdgcn_exp2f(sa[g][3]);
      float e4 = __builtin_amdgcn_exp2f(sb[g][0]);
      float e5 = __builtin_amdgcn_exp2f(sb[g][1]);
      float e6 = __builtin_amdgcn_exp2f(sb[g][2]);
      float e7 = __builtin_amdgcn_exp2f(sb[g][3]);
      pf[g].i[0] = pack_bf16_trunc(e0, e1);
      pf[g].i[1] = pack_bf16_trunc(e2, e3);
      pf[g].i[2] = pack_bf16_trunc(e4, e5);
      pf[g].i[3] = pack_bf16_trunc(e6, e7);
    }

    #pragma unroll
    for (int g = 0; g < 4; g++) {
      o_lo[g] = __builtin_amdgcn_mfma_f32_16x16x32_bf16(vlo.b, pf[g].b, o_lo[g], 0, 0, 0);
      o_hi[g] = __builtin_amdgcn_mfma_f32_16x16x32_bf16(vhi.b, pf[g].b, o_hi[g], 0, 0, 0);
      lacc[g] = __builtin_amdgcn_mfma_f32_16x16x32_bf16(ones.b, pf[g].b, lacc[g], 0, 0, 0);
    }

    ka_c = ka_n; kb_c = kb_n; ba_c = ba_n; bb_c = bb_n;
  }

  // ---- cross-wave reduction (one LDS round-trip) ----
  #pragma unroll
  for (int g = 0; g < 4; g++) {
    int q = g * 16 + l16;
    #pragma unroll
    for (int r = 0; r < 4; r++) {
      red_o[wave][q][quad * 4 + r]      = o_lo[g][r];
      red_o[wave][q][16 + quad * 4 + r] = o_hi[g][r];
    }
    if (quad == 0) red_l[wave][q] = lacc[g][0];  // all rows equal = l(q)
  }
  __syncthreads();

  // wave w reduces q-group g = w
  int q = wave * 16 + l16;
  float lt = red_l[0][q] + red_l[1][q] + red_l[2][q] + red_l[3][q];
  float inv = 1.0f / lt;
  f32x4 slo = {0.f, 0.f, 0.f, 0.f}, shi = {0.f, 0.f, 0.f, 0.f};
  #pragma unroll
  for (int src = 0; src < 4; src++) {
    #pragma unroll
    for (int r = 0; r < 4; r++) {
      slo[r] += red_o[src][q][quad * 4 + r];
      shi[r] += red_o[src][q][16 + quad * 4 + r];
    }
  }
  union { s16x4 s; __bf16 h[4]; } u1, u2;
  #pragma unroll
  for (int r = 0; r < 4; r++) {
    u1.h[r] = (__bf16)(slo[r] * inv);
    u2.h[r] = (__bf16)(shi[r] * inv);
  }
  __bf16* orow = ob + (size_t)(q0 + q) * XB_STRIDE + head * HD;
  *(s16x4*)(orow + quad * 4)      = u1.s;
  *(s16x4*)(orow + 16 + quad * 4) = u2.s;
}

// ---------------------------------------------------------------------------
// Output projection (pipelined): out = (keep ? attn@Wp^T + b : 0) + x
__global__ __launch_bounds__(256) void proj_gemm(const __bf16* __restrict__ ob,
                                                 const __bf16* __restrict__ wb,
                                                 const float* __restrict__ pb,
                                                 const int* __restrict__ keepi,
                                                 const float* __restrict__ x,
                                                 float* __restrict__ out) {
  int wave = threadIdx.x >> 6, lane = threadIdx.x & 63;
  int quad = lane >> 4, l16 = lane & 15;
  int m0 = blockIdx.x * 64 + wave * 16;
  int n0 = blockIdx.y * 64;

  const __bf16* arow = ob + (size_t)(m0 + l16) * XB_STRIDE + quad * 8;
  const __bf16* wrow = wb + (size_t)(n0 + l16) * XB_STRIDE + quad * 8;

  FragI ac, wc[4];
  ac.i = *(const i32x4*)(arow);
  #pragma unroll
  for (int nt = 0; nt < 4; nt++)
    wc[nt].i = *(const i32x4*)(wrow + (size_t)nt * 16 * XB_STRIDE);

  f32x4 acc[4] = {};
  for (int kk = 0; kk < CDIM; kk += 32) {
    int kn = (kk + 32 < CDIM) ? kk + 32 : 0;
    FragI an, wn[4];
    an.i = *(const i32x4*)(arow + kn);
    #pragma unroll
    for (int nt = 0; nt < 4; nt++)
      wn[nt].i = *(const i32x4*)(wrow + (size_t)nt * 16 * XB_STRIDE + kn);
    #pragma unroll
    for (int nt = 0; nt < 4; nt++)
      acc[nt] = __builtin_amdgcn_mfma_f32_16x16x32_bf16(wc[nt].b, ac.b, acc[nt], 0, 0, 0);
    ac = an;
    #pragma unroll
    for (int nt = 0; nt < 4; nt++) wc[nt] = wn[nt];
  }
  // D[channel][token]: row = channel quad*4+r, col = token l16
  int m = m0 + l16;
  int keep = keepi[m];
  #pragma unroll
  for (int nt = 0; nt < 4; nt++) {
    int c0 = n0 + nt * 16 + quad * 4;
    #pragma unroll
    for (int r = 0; r < 4; r++) {
      float v = acc[nt][r] + pb[c0 + r];
      v = keep ? v : 0.0f;
      out[(size_t)m * CDIM + c0 + r] = v + x[(size_t)m * CDIM + c0 + r];
    }
  }
}

// ---------------------------------------------------------------------------
extern "C" void kernel_launch(void* const* d_in, const int* in_sizes, int n_in,
                              void* d_out, int out_size, void* d_ws, size_t ws_size,
                              hipStream_t stream) {
  const float* x      = (const float*)d_in[0];
  const float* dbz    = (const float*)d_in[1];
  const float* qkv_w  = (const float*)d_in[2];
  const float* proj_w = (const float*)d_in[3];
  const float* proj_b = (const float*)d_in[4];
  float* out = (float*)d_out;

  char* w = (char*)d_ws;
  __bf16* xb     = (__bf16*)(w);                        // 4096x272x2 = 2.23MB
  __bf16* qb     = (__bf16*)(w + (3u << 20));           // 2MB
  __bf16* kb     = (__bf16*)(w + (5u << 20));           // 2MB
  __bf16* vt     = (__bf16*)(w + (7u << 20));           // 8*32*4128*2 = 2.02MB
  __bf16* ob     = (__bf16*)(w + (9u << 20) + (512u << 10));  // 2.23MB
  __bf16* wqkvb  = (__bf16*)(w + (12u << 20));          // 768x272x2 = 417KB
  __bf16* wprojb = (__bf16*)(w + (12u << 20) + (512u << 10)); // 139KB
  float*  bias   = (float*)(w + (13u << 20));           // 16KB
  int*    keepi  = (int*)(w + (13u << 20) + 16384);     // 16KB

  fused_prep<<<dim3(SEG_M / 256), dim3(256), 0, stream>>>(
      x, qkv_w, proj_w, dbz, xb, wqkvb, wprojb, bias, keepi);
  qkv_gemm<<<dim3(N_TOK / 64, QKV_N / 64), dim3(256), 0, stream>>>(
      xb, wqkvb, qb, kb, vt);
  attn_kernel<<<dim3((N_TOK / 64) * NH), dim3(256), 0, stream>>>(
      qb, kb, vt, bias, ob);
  proj_gemm<<<dim3(N_TOK / 64, CDIM / 64), dim3(256), 0, stream>>>(
      ob, wprojb, proj_b, keepi, x, out);
}

// Round 8
// 112.809 us; speedup vs baseline: 2.3014x; 1.0077x over previous
//
#include <hip/hip_runtime.h>
#include <hip/hip_bf16.h>

#define N_TOK 4096
#define NH 8
#define HD 32
#define CDIM 256
#define QKV_N 768
#define VT_STRIDE 4128   // padded global V^T row: breaks power-of-2 channel/set alias
#define XB_STRIDE 272    // padded rows for xb/ob/weight scratch (breaks 512B stride)
#define SCALE_F 0.17677669529663687f
#define LOG2E   1.4426950408889634f

typedef float  f32x4  __attribute__((ext_vector_type(4)));
typedef int    i32x4  __attribute__((ext_vector_type(4)));
typedef short  s16x4  __attribute__((ext_vector_type(4)));
typedef __bf16 bf16x8 __attribute__((ext_vector_type(8)));

union FragI { i32x4 i; bf16x8 b; };
union FragH { struct { s16x4 lo, hi; } s; bf16x8 b; };

// pack two f32 into bf16x2 by truncation: ONE v_perm_b32.
__device__ inline int pack_bf16_trunc(float a, float b) {
  return (int)__builtin_amdgcn_perm(__builtin_bit_cast(unsigned, b),
                                    __builtin_bit_cast(unsigned, a),
                                    0x07060302u);
}

// ---------------------------------------------------------------------------
// fused prep: x->bf16 (rows padded to 272), qkv_w->bf16 (Q rows pre-scaled by
// SCALE*log2e), proj_w->bf16, keep-mask -> bias/keepi.
#define SEG_X 1048576
#define SEG_W (SEG_X + 196608)
#define SEG_P (SEG_W + 65536)
#define SEG_M (SEG_P + 4096)
__global__ __launch_bounds__(256) void fused_prep(const float* __restrict__ x,
                                                  const float* __restrict__ qkv_w,
                                                  const float* __restrict__ proj_w,
                                                  const float* __restrict__ dbz,
                                                  __bf16* __restrict__ xb,
                                                  __bf16* __restrict__ wqkvb,
                                                  __bf16* __restrict__ wprojb,
                                                  float* __restrict__ bias,
                                                  int* __restrict__ keepi) {
  int gid = blockIdx.x * 256 + threadIdx.x;
  if (gid < SEG_X) {
    xb[(gid >> 8) * XB_STRIDE + (gid & 255)] = (__bf16)x[gid];
  } else if (gid < SEG_W) {
    int i = gid - SEG_X;
    float s = ((i >> 8) < 256) ? (SCALE_F * LOG2E) : 1.0f;   // Q output rows
    wqkvb[(i >> 8) * XB_STRIDE + (i & 255)] = (__bf16)(qkv_w[i] * s);
  } else if (gid < SEG_P) {
    int i = gid - SEG_W;
    wprojb[(i >> 8) * XB_STRIDE + (i & 255)] = (__bf16)proj_w[i];
  } else if (gid < SEG_M) {
    int n = gid - SEG_P;
    int t = n >> 10, rc = n & 1023, r = rc >> 5, c = rc & 31;
    bool keep = false;
    #pragma unroll
    for (int dr = -1; dr <= 1; dr++)
      #pragma unroll
      for (int dc = -1; dc <= 1; dc++) {
        int rr = r + dr, cc = c + dc;
        if (rr >= 0 && rr < 32 && cc >= 0 && cc < 32)
          keep = keep || (dbz[t * 1024 + rr * 32 + cc] >= 15.0f);
      }
    bias[n]  = keep ? 0.0f : -30000.0f;   // exp2(s-30000) == 0 exactly
    keepi[n] = keep ? 1 : 0;
  }
}

// ---------------------------------------------------------------------------
// QKV GEMM, operand-swapped (D[channel][token]), software-pipelined k-loop.
__global__ __launch_bounds__(256) void qkv_gemm(const __bf16* __restrict__ xb,
                                                const __bf16* __restrict__ wb,
                                                __bf16* __restrict__ qb,
                                                __bf16* __restrict__ kb,
                                                __bf16* __restrict__ vt) {
  int wave = threadIdx.x >> 6, lane = threadIdx.x & 63;
  int quad = lane >> 4, l16 = lane & 15;
  int m0 = blockIdx.x * 64 + wave * 16;   // tokens
  int n0 = blockIdx.y * 64;               // output channels

  const __bf16* xrow = xb + (size_t)(m0 + l16) * XB_STRIDE + quad * 8;
  const __bf16* wrow = wb + (size_t)(n0 + l16) * XB_STRIDE + quad * 8;

  FragI xc, wc[4];
  xc.i = *(const i32x4*)(xrow);
  #pragma unroll
  for (int nt = 0; nt < 4; nt++)
    wc[nt].i = *(const i32x4*)(wrow + (size_t)nt * 16 * XB_STRIDE);

  f32x4 acc[4] = {};
  for (int kk = 0; kk < CDIM; kk += 32) {
    int kn = (kk + 32 < CDIM) ? kk + 32 : 0;      // last prefetch unused
    FragI xn, wn[4];
    xn.i = *(const i32x4*)(xrow + kn);
    #pragma unroll
    for (int nt = 0; nt < 4; nt++)
      wn[nt].i = *(const i32x4*)(wrow + (size_t)nt * 16 * XB_STRIDE + kn);
    #pragma unroll
    for (int nt = 0; nt < 4; nt++)
      acc[nt] = __builtin_amdgcn_mfma_f32_16x16x32_bf16(wc[nt].b, xc.b, acc[nt], 0, 0, 0);
    xc = xn;
    #pragma unroll
    for (int nt = 0; nt < 4; nt++) wc[nt] = wn[nt];
  }
  int m = m0 + l16;
  #pragma unroll
  for (int nt = 0; nt < 4; nt++) {
    int cbase = n0 + nt * 16 + quad * 4;       // 4 consecutive channels
    int which = cbase >> 8, rem = cbase & 255, hd = rem >> 5, d0 = rem & 31;
    if (which < 2) {
      union { s16x4 s; __bf16 h[4]; } u;
      #pragma unroll
      for (int r = 0; r < 4; r++) u.h[r] = (__bf16)acc[nt][r];
      __bf16* dst = (which == 0 ? qb : kb) + ((size_t)hd * N_TOK + m) * HD + d0;
      *(s16x4*)dst = u.s;
    } else {
      #pragma unroll
      for (int r = 0; r < 4; r++)
        vt[(size_t)(hd * HD + d0 + r) * VT_STRIDE + m] = (__bf16)acc[nt][r];
    }
  }
}

// ---------------------------------------------------------------------------
// Attention v7: waves split KEYS (wave-private K/V, no LDS/barriers in loop,
// Q register-stationary). v7 change: V (and bias) prefetched a FULL iteration
// ahead like K -- every operand of iteration t is in registers before t
// starts, so the scattered V global-load latency is covered by an entire
// iteration (~700+ cyc wall at 2 waves/SIMD) instead of ~150 cyc.
__global__ __launch_bounds__(256, 2) void attn_kernel(const __bf16* __restrict__ qb,
                                                      const __bf16* __restrict__ kb,
                                                      const __bf16* __restrict__ vt,
                                                      const float* __restrict__ bias,
                                                      __bf16* __restrict__ ob) {
  __shared__ float red_o[4][64][34];   // stride 34 words: 8B-aligned, 4-way max
  __shared__ float red_l[4][64];

  int b = blockIdx.x;
  int head = b & 7, qx = b >> 3;       // 512 blocks = 2/CU exactly; head%8 -> XCD affinity
  int wave = threadIdx.x >> 6, lane = threadIdx.x & 63;
  int quad = lane >> 4, l16 = lane & 15;
  int q0 = qx * 64;

  const __bf16* qh = qb + (size_t)head * N_TOK * HD;
  const __bf16* kh = kb + (size_t)head * N_TOK * HD;
  const __bf16* vh = vt + (size_t)head * HD * VT_STRIDE;

  FragI qf[4];
  #pragma unroll
  for (int g = 0; g < 4; g++)
    qf[g].i = *(const i32x4*)(qh + (size_t)(q0 + g * 16 + l16) * HD + quad * 8);

  FragI ones;
  #pragma unroll
  for (int j = 0; j < 8; j++) ones.b[j] = (__bf16)1.0f;

  f32x4 o_lo[4] = {}, o_hi[4] = {}, lacc[4] = {};

  // iteration-0 operands: K, bias, AND V all prefetched
  FragI ka_c, kb_c;
  f32x4 ba_c, bb_c;
  FragH vlo_c, vhi_c;
  {
    int k0 = wave * 32;
    ka_c.i = *(const i32x4*)(kh + (size_t)(k0 + l16) * HD + quad * 8);
    kb_c.i = *(const i32x4*)(kh + (size_t)(k0 + 16 + l16) * HD + quad * 8);
    ba_c = *(const f32x4*)(bias + k0 + quad * 4);
    bb_c = *(const f32x4*)(bias + k0 + 16 + quad * 4);
    const __bf16* vp = vh + (size_t)l16 * VT_STRIDE + k0 + quad * 4;
    vlo_c.s.lo = *(const s16x4*)(vp);
    vlo_c.s.hi = *(const s16x4*)(vp + 16);
    const __bf16* vp2 = vh + (size_t)(16 + l16) * VT_STRIDE + k0 + quad * 4;
    vhi_c.s.lo = *(const s16x4*)(vp2);
    vhi_c.s.hi = *(const s16x4*)(vp2 + 16);
  }

  for (int t = 0; t < 32; t++) {
    int kc = wave * 32 + t * 128;
    int kn = (t < 31) ? kc + 128 : wave * 32;   // wrap: last prefetch unused

    // issue ALL next-iteration loads first (independent of current compute)
    FragI ka_n, kb_n;
    f32x4 ba_n, bb_n;
    FragH vlo_n, vhi_n;
    ka_n.i = *(const i32x4*)(kh + (size_t)(kn + l16) * HD + quad * 8);
    kb_n.i = *(const i32x4*)(kh + (size_t)(kn + 16 + l16) * HD + quad * 8);
    ba_n = *(const f32x4*)(bias + kn + quad * 4);
    bb_n = *(const f32x4*)(bias + kn + 16 + quad * 4);
    {
      const __bf16* vp = vh + (size_t)l16 * VT_STRIDE + kn + quad * 4;
      vlo_n.s.lo = *(const s16x4*)(vp);
      vlo_n.s.hi = *(const s16x4*)(vp + 16);
      const __bf16* vp2 = vh + (size_t)(16 + l16) * VT_STRIDE + kn + quad * 4;
      vhi_n.s.lo = *(const s16x4*)(vp2);
      vhi_n.s.hi = *(const s16x4*)(vp2 + 16);
    }

    // S^T per q-group: D[key][q] init = bias(key)
    f32x4 sa[4], sb[4];
    #pragma unroll
    for (int g = 0; g < 4; g++) {
      sa[g] = __builtin_amdgcn_mfma_f32_16x16x32_bf16(ka_c.b, qf[g].b, ba_c, 0, 0, 0);
      sb[g] = __builtin_amdgcn_mfma_f32_16x16x32_bf16(kb_c.b, qf[g].b, bb_c, 0, 0, 0);
    }

    FragI pf[4];
    #pragma unroll
    for (int g = 0; g < 4; g++) {
      float e0 = __builtin_amdgcn_exp2f(sa[g][0]);
      float e1 = __builtin_amdgcn_exp2f(sa[g][1]);
      float e2 = __builtin_amdgcn_exp2f(sa[g][2]);
      float e3 = __builtin_amdgcn_exp2f(sa[g][3]);
      float e4 = __builtin_amdgcn_exp2f(sb[g][0]);
      float e5 = __builtin_amdgcn_exp2f(sb[g][1]);
      float e6 = __builtin_amdgcn_exp2f(sb[g][2]);
      float e7 = __builtin_amdgcn_exp2f(sb[g][3]);
      pf[g].i[0] = pack_bf16_trunc(e0, e1);
      pf[g].i[1] = pack_bf16_trunc(e2, e3);
      pf[g].i[2] = pack_bf16_trunc(e4, e5);
      pf[g].i[3] = pack_bf16_trunc(e6, e7);
    }

    #pragma unroll
    for (int g = 0; g < 4; g++) {
      o_lo[g] = __builtin_amdgcn_mfma_f32_16x16x32_bf16(vlo_c.b, pf[g].b, o_lo[g], 0, 0, 0);
      o_hi[g] = __builtin_amdgcn_mfma_f32_16x16x32_bf16(vhi_c.b, pf[g].b, o_hi[g], 0, 0, 0);
      lacc[g] = __builtin_amdgcn_mfma_f32_16x16x32_bf16(ones.b, pf[g].b, lacc[g], 0, 0, 0);
    }

    ka_c = ka_n; kb_c = kb_n; ba_c = ba_n; bb_c = bb_n;
    vlo_c = vlo_n; vhi_c = vhi_n;
  }

  // ---- cross-wave reduction (one LDS round-trip) ----
  #pragma unroll
  for (int g = 0; g < 4; g++) {
    int q = g * 16 + l16;
    #pragma unroll
    for (int r = 0; r < 4; r++) {
      red_o[wave][q][quad * 4 + r]      = o_lo[g][r];
      red_o[wave][q][16 + quad * 4 + r] = o_hi[g][r];
    }
    if (quad == 0) red_l[wave][q] = lacc[g][0];  // all rows equal = l(q)
  }
  __syncthreads();

  // wave w reduces q-group g = w
  int q = wave * 16 + l16;
  float lt = red_l[0][q] + red_l[1][q] + red_l[2][q] + red_l[3][q];
  float inv = 1.0f / lt;
  f32x4 slo = {0.f, 0.f, 0.f, 0.f}, shi = {0.f, 0.f, 0.f, 0.f};
  #pragma unroll
  for (int src = 0; src < 4; src++) {
    #pragma unroll
    for (int r = 0; r < 4; r++) {
      slo[r] += red_o[src][q][quad * 4 + r];
      shi[r] += red_o[src][q][16 + quad * 4 + r];
    }
  }
  union { s16x4 s; __bf16 h[4]; } u1, u2;
  #pragma unroll
  for (int r = 0; r < 4; r++) {
    u1.h[r] = (__bf16)(slo[r] * inv);
    u2.h[r] = (__bf16)(shi[r] * inv);
  }
  __bf16* orow = ob + (size_t)(q0 + q) * XB_STRIDE + head * HD;
  *(s16x4*)(orow + quad * 4)      = u1.s;
  *(s16x4*)(orow + 16 + quad * 4) = u2.s;
}

// ---------------------------------------------------------------------------
// Output projection (pipelined): out = (keep ? attn@Wp^T + b : 0) + x
__global__ __launch_bounds__(256) void proj_gemm(const __bf16* __restrict__ ob,
                                                 const __bf16* __restrict__ wb,
                                                 const float* __restrict__ pb,
                                                 const int* __restrict__ keepi,
                                                 const float* __restrict__ x,
                                                 float* __restrict__ out) {
  int wave = threadIdx.x >> 6, lane = threadIdx.x & 63;
  int quad = lane >> 4, l16 = lane & 15;
  int m0 = blockIdx.x * 64 + wave * 16;
  int n0 = blockIdx.y * 64;

  const __bf16* arow = ob + (size_t)(m0 + l16) * XB_STRIDE + quad * 8;
  const __bf16* wrow = wb + (size_t)(n0 + l16) * XB_STRIDE + quad * 8;

  FragI ac, wc[4];
  ac.i = *(const i32x4*)(arow);
  #pragma unroll
  for (int nt = 0; nt < 4; nt++)
    wc[nt].i = *(const i32x4*)(wrow + (size_t)nt * 16 * XB_STRIDE);

  f32x4 acc[4] = {};
  for (int kk = 0; kk < CDIM; kk += 32) {
    int kn = (kk + 32 < CDIM) ? kk + 32 : 0;
    FragI an, wn[4];
    an.i = *(const i32x4*)(arow + kn);
    #pragma unroll
    for (int nt = 0; nt < 4; nt++)
      wn[nt].i = *(const i32x4*)(wrow + (size_t)nt * 16 * XB_STRIDE + kn);
    #pragma unroll
    for (int nt = 0; nt < 4; nt++)
      acc[nt] = __builtin_amdgcn_mfma_f32_16x16x32_bf16(wc[nt].b, ac.b, acc[nt], 0, 0, 0);
    ac = an;
    #pragma unroll
    for (int nt = 0; nt < 4; nt++) wc[nt] = wn[nt];
  }
  // D[channel][token]: row = channel quad*4+r, col = token l16
  int m = m0 + l16;
  int keep = keepi[m];
  #pragma unroll
  for (int nt = 0; nt < 4; nt++) {
    int c0 = n0 + nt * 16 + quad * 4;
    #pragma unroll
    for (int r = 0; r < 4; r++) {
      float v = acc[nt][r] + pb[c0 + r];
      v = keep ? v : 0.0f;
      out[(size_t)m * CDIM + c0 + r] = v + x[(size_t)m * CDIM + c0 + r];
    }
  }
}

// ---------------------------------------------------------------------------
extern "C" void kernel_launch(void* const* d_in, const int* in_sizes, int n_in,
                              void* d_out, int out_size, void* d_ws, size_t ws_size,
                              hipStream_t stream) {
  const float* x      = (const float*)d_in[0];
  const float* dbz    = (const float*)d_in[1];
  const float* qkv_w  = (const float*)d_in[2];
  const float* proj_w = (const float*)d_in[3];
  const float* proj_b = (const float*)d_in[4];
  float* out = (float*)d_out;

  char* w = (char*)d_ws;
  __bf16* xb     = (__bf16*)(w);                        // 4096x272x2 = 2.23MB
  __bf16* qb     = (__bf16*)(w + (3u << 20));           // 2MB
  __bf16* kb     = (__bf16*)(w + (5u << 20));           // 2MB
  __bf16* vt     = (__bf16*)(w + (7u << 20));           // 8*32*4128*2 = 2.02MB
  __bf16* ob     = (__bf16*)(w + (9u << 20) + (512u << 10));  // 2.23MB
  __bf16* wqkvb  = (__bf16*)(w + (12u << 20));          // 768x272x2 = 417KB
  __bf16* wprojb = (__bf16*)(w + (12u << 20) + (512u << 10)); // 139KB
  float*  bias   = (float*)(w + (13u << 20));           // 16KB
  int*    keepi  = (int*)(w + (13u << 20) + 16384);     // 16KB

  fused_prep<<<dim3(SEG_M / 256), dim3(256), 0, stream>>>(
      x, qkv_w, proj_w, dbz, xb, wqkvb, wprojb, bias, keepi);
  qkv_gemm<<<dim3(N_TOK / 64, QKV_N / 64), dim3(256), 0, stream>>>(
      xb, wqkvb, qb, kb, vt);
  attn_kernel<<<dim3((N_TOK / 64) * NH), dim3(256), 0, stream>>>(
      qb, kb, vt, bias, ob);
  proj_gemm<<<dim3(N_TOK / 64, CDIM / 64), dim3(256), 0, stream>>>(
      ob, wprojb, proj_b, keepi, x, out);
}